// Round 7
// baseline (503.936 us; speedup 1.0000x reference)
//
#include <hip/hip_runtime.h>

#define BB 2
#define NTOK 21952      // 28^3
#define CC 96
#define WD 784          // 28*28
#define NSR 343         // 7^3
#define NSITE 686       // BB*NSR
#define SCALE 0.25f
#define LN_EPS 1e-5f

typedef _Float16 half_t;
typedef __attribute__((ext_vector_type(2))) _Float16 h2;
typedef __attribute__((ext_vector_type(8))) _Float16 h8;
union HU { h8 v; h2 p[4]; };

// ---------------------------------------------------------------------------
// K0: transpose sr_w [96][6144] -> Wt4[1536][96] (float4 over 4 consecutive k)
// ---------------------------------------------------------------------------
__global__ __launch_bounds__(256) void k_wt(
    const float* __restrict__ w, float4* __restrict__ Wt4)
{
    const int id = blockIdx.x * 256 + threadIdx.x;
    if (id >= 96 * 1536) return;
    const int co = id % 96, kbg = id / 96;
    const float4 v = *(const float4*)(w + (size_t)co * 6144 + 4 * kbg);
    Wt4[(size_t)kbg * 96 + co] = v;
}

// ---------------------------------------------------------------------------
// K1: P[token][288] = x @ [lepe_lin | q1 | q2 | kv2]^T  (+ lepe bias on 0:96)
// ---------------------------------------------------------------------------
__global__ __launch_bounds__(192) void k_proj(
    const float* __restrict__ x, const float* __restrict__ lepe_w,
    const float* __restrict__ lepe_b, const float* __restrict__ q1_w,
    const float* __restrict__ q2_w, const float* __restrict__ kv2_w,
    float* __restrict__ P)
{
    __shared__ float xT[96][68];   // [k][t]
    __shared__ float wT[96][52];   // [k][j]

    const int base = blockIdx.x * 64;
    const int j0 = blockIdx.y * 48;

    for (int it = threadIdx.x; it < 1536; it += 192) {
        int cq = it % 24, t = it / 24;
        float4 v = *(const float4*)(x + (size_t)(base + t) * 96 + cq * 4);
        xT[cq * 4 + 0][t] = v.x; xT[cq * 4 + 1][t] = v.y;
        xT[cq * 4 + 2][t] = v.z; xT[cq * 4 + 3][t] = v.w;
    }
    for (int it = threadIdx.x; it < 1152; it += 192) {
        int cq = it % 24, jl = it / 24;
        int jg = j0 + jl;
        const float* wrow;
        if (jg < 96)       wrow = lepe_w + jg * 96;
        else if (jg < 144) wrow = q1_w + (jg - 96) * 96;
        else if (jg < 192) wrow = q2_w + (jg - 144) * 96;
        else               wrow = kv2_w + (jg - 192) * 96;
        float4 v = *(const float4*)(wrow + cq * 4);
        wT[cq * 4 + 0][jl] = v.x; wT[cq * 4 + 1][jl] = v.y;
        wT[cq * 4 + 2][jl] = v.z; wT[cq * 4 + 3][jl] = v.w;
    }
    __syncthreads();

    const int tq = threadIdx.x & 15;
    const int jq = threadIdx.x >> 4;
    float acc[4][4];
#pragma unroll
    for (int i = 0; i < 4; i++)
#pragma unroll
        for (int jj = 0; jj < 4; jj++) acc[i][jj] = 0.f;

    for (int c = 0; c < 96; c++) {
        float4 xv = *(const float4*)(&xT[c][tq * 4]);
        float4 wv = *(const float4*)(&wT[c][jq * 4]);
        float xa[4] = {xv.x, xv.y, xv.z, xv.w};
        float wa[4] = {wv.x, wv.y, wv.z, wv.w};
#pragma unroll
        for (int i = 0; i < 4; i++)
#pragma unroll
            for (int jj = 0; jj < 4; jj++) acc[i][jj] += xa[i] * wa[jj];
    }

    float bias[4];
#pragma unroll
    for (int jj = 0; jj < 4; jj++) {
        int jg = j0 + jq * 4 + jj;
        bias[jj] = (jg < 96) ? lepe_b[jg] : 0.f;
    }
#pragma unroll
    for (int i = 0; i < 4; i++) {
        int t = base + tq * 4 + i;
        float4 o = make_float4(acc[i][0] + bias[0], acc[i][1] + bias[1],
                               acc[i][2] + bias[2], acc[i][3] + bias[3]);
        *(float4*)(P + (size_t)t * 288 + j0 + jq * 4) = o;
    }
}

// ---------------------------------------------------------------------------
// K2a: SR conv split-K GEMM. grid (86 site-groups x 16 k-splits), block 128.
// ---------------------------------------------------------------------------
__global__ __launch_bounds__(128) void k_sr_a(
    const float* __restrict__ x, const float4* __restrict__ Wt4,
    float* __restrict__ pa)
{
    __shared__ float patch[8 * 384];
    const int sg = blockIdx.x, ks = blockIdx.y;
    const int ci0 = ks * 6;

    for (int pr = threadIdx.x; pr < 512; pr += 128) {
        int s = pr >> 6, p = pr & 63;
        int s_g = sg * 8 + s; if (s_g > NSITE - 1) s_g = NSITE - 1;
        int b = s_g / NSR, sloc = s_g % NSR;
        int si = sloc / 49, sj = (sloc / 7) % 7, sk = sloc % 7;
        int a = p >> 4, q = (p >> 2) & 3, r = p & 3;
        int n = (4 * si + a) * WD + (4 * sj + q) * 28 + (4 * sk + r);
        const float2* xp = (const float2*)(x + ((size_t)b * NTOK + n) * 96 + ci0);
        float2 v0 = xp[0], v1 = xp[1], v2 = xp[2];
        int base = s * 384 + p;
        patch[base +   0] = v0.x; patch[base +  64] = v0.y;
        patch[base + 128] = v1.x; patch[base + 192] = v1.y;
        patch[base + 256] = v2.x; patch[base + 320] = v2.y;
    }
    __syncthreads();

    const int co = threadIdx.x;
    if (co >= 96) return;
    float acc[8];
#pragma unroll
    for (int s = 0; s < 8; s++) acc[s] = 0.f;
    const float4* p4 = (const float4*)patch;
    const float4* wb = Wt4 + (size_t)ks * 96 * 96 + co;
    for (int kb = 0; kb < 96; kb++) {
        float4 w = wb[(size_t)kb * 96];
#pragma unroll
        for (int s = 0; s < 8; s++) {
            float4 pv = p4[s * 96 + kb];
            acc[s] += pv.x * w.x + pv.y * w.y + pv.z * w.z + pv.w * w.w;
        }
    }
#pragma unroll
    for (int s = 0; s < 8; s++) {
        int s_g = sg * 8 + s;
        if (s_g < NSITE)
            pa[((size_t)s_g * 16 + ks) * 96 + co] = acc[s];
    }
}

// ---------------------------------------------------------------------------
// K2b: reduce 16 partials + bias + LN + GELU + kv1 -> k1/v1 [B][3][343][16]
// ---------------------------------------------------------------------------
__global__ __launch_bounds__(96) void k_sr_b(
    const float* __restrict__ pa, const float* __restrict__ sr_b,
    const float* __restrict__ norm_g, const float* __restrict__ norm_b,
    const float* __restrict__ kv1_w, float* __restrict__ k1,
    float* __restrict__ v1)
{
    __shared__ float xs_s[96];
    __shared__ float gx[96];
    const int s_g = blockIdx.x;
    const int b = s_g / NSR, s = s_g % NSR;
    const int co = threadIdx.x;

    const float* pp = pa + (size_t)s_g * 16 * 96 + co;
    float acc = sr_b[co];
#pragma unroll
    for (int ks = 0; ks < 16; ks++) acc += pp[ks * 96];
    xs_s[co] = acc;
    __syncthreads();

    float m = 0.f, m2 = 0.f;
    for (int c = 0; c < 96; c++) { float v = xs_s[c]; m += v; m2 += v * v; }
    m *= (1.f / 96.f);
    float var = m2 * (1.f / 96.f) - m * m;
    float t = (acc - m) * rsqrtf(var + LN_EPS) * norm_g[co] + norm_b[co];
    gx[co] = 0.5f * t * (1.f + erff(t * 0.70710678118654752f));
    __syncthreads();

    const float4* w4 = (const float4*)(kv1_w + co * 96);
    const float4* g4 = (const float4*)gx;
    float a2 = 0.f;
#pragma unroll
    for (int c = 0; c < 24; c++) {
        float4 w = w4[c]; float4 g = g4[c];
        a2 += g.x * w.x + g.y * w.y + g.z * w.z + g.w * w.w;
    }
    int pair = co / 48, h = (co % 48) / 16, e = co % 16;
    float* dst = pair ? v1 : k1;
    dst[(((size_t)b * 3 + h) * NSR + s) * 16 + e] = a2;
}

// ---------------------------------------------------------------------------
// helpers
// ---------------------------------------------------------------------------
__device__ __forceinline__ void ld16_g(const float* p, float* o) {
    const float4* p4 = (const float4*)p;
#pragma unroll
    for (int i = 0; i < 4; i++) {
        float4 v = p4[i];
        o[4 * i] = v.x; o[4 * i + 1] = v.y; o[4 * i + 2] = v.z; o[4 * i + 3] = v.w;
    }
}
__device__ __forceinline__ void st16_g(float* p, const float* o, float scl) {
    float4* p4 = (float4*)p;
#pragma unroll
    for (int i = 0; i < 4; i++)
        p4[i] = make_float4(o[4 * i] * scl, o[4 * i + 1] * scl,
                            o[4 * i + 2] * scl, o[4 * i + 3] * scl);
}
__device__ __forceinline__ void cvt_q(const float* qa, h2* qh) {
#pragma unroll
    for (int i = 0; i < 8; i++) {
        h2 t; t[0] = (half_t)qa[2 * i]; t[1] = (half_t)qa[2 * i + 1];
        qh[i] = t;
    }
}

// ---------------------------------------------------------------------------
// attention core: 2 queries/thread over 343 keys, K/V as f16 in LDS.
// per key per wave: 4 ds_read_b128 (vs 8 for fp32) — LDS-pipe relief.
// ---------------------------------------------------------------------------
__device__ __forceinline__ void attn_core2(
    const h2* kl2, const h2* vl2, const h2* q0h, const h2* q1h,
    float* a0, float* a1, float& l0, float& l1)
{
    const h8* kp = (const h8*)kl2;
    const h8* vp = (const h8*)vl2;
    for (int m = 0; m < NSR; m++) {
        HU ka, kb, va, vb;
        ka.v = kp[2 * m]; kb.v = kp[2 * m + 1];
        va.v = vp[2 * m]; vb.v = vp[2 * m + 1];
        float s0 = 0.f, s1 = 0.f;
#pragma unroll
        for (int i = 0; i < 4; i++) {
            s0 = __builtin_amdgcn_fdot2(q0h[i], ka.p[i], s0, false);
            s0 = __builtin_amdgcn_fdot2(q0h[4 + i], kb.p[i], s0, false);
            s1 = __builtin_amdgcn_fdot2(q1h[i], ka.p[i], s1, false);
            s1 = __builtin_amdgcn_fdot2(q1h[4 + i], kb.p[i], s1, false);
        }
        float p0 = __expf(s0 * SCALE), p1 = __expf(s1 * SCALE);
        l0 += p0; l1 += p1;
#pragma unroll
        for (int i = 0; i < 4; i++) {
            a0[2 * i]     += p0 * (float)va.p[i][0];
            a0[2 * i + 1] += p0 * (float)va.p[i][1];
            a0[8 + 2 * i]     += p0 * (float)vb.p[i][0];
            a0[8 + 2 * i + 1] += p0 * (float)vb.p[i][1];
            a1[2 * i]     += p1 * (float)va.p[i][0];
            a1[2 * i + 1] += p1 * (float)va.p[i][1];
            a1[8 + 2 * i]     += p1 * (float)vb.p[i][0];
            a1[8 + 2 * i + 1] += p1 * (float)vb.p[i][1];
        }
    }
}

// ---------------------------------------------------------------------------
// K3: branch-1 SR attention -> y[:, :, 0:48]
// grid (6, 86), 128 threads, 2 queries/thread.
// ---------------------------------------------------------------------------
__global__ __launch_bounds__(128) void k_attn1(
    const float* __restrict__ P, const float* __restrict__ k1,
    const float* __restrict__ v1, float* __restrict__ y)
{
    __shared__ h2 kl2[NSR * 8];
    __shared__ h2 vl2[NSR * 8];
    const int bh = blockIdx.x;
    const int b = bh / 3, h = bh % 3;
    const float4* ks = (const float4*)(k1 + (size_t)bh * NSR * 16);
    const float4* vs = (const float4*)(v1 + (size_t)bh * NSR * 16);
    for (int idx = threadIdx.x; idx < NSR * 4; idx += 128) {
        float4 kv = ks[idx];
        float4 vv = vs[idx];
        h2 t;
        t[0] = (half_t)kv.x; t[1] = (half_t)kv.y; kl2[2 * idx] = t;
        t[0] = (half_t)kv.z; t[1] = (half_t)kv.w; kl2[2 * idx + 1] = t;
        t[0] = (half_t)vv.x; t[1] = (half_t)vv.y; vl2[2 * idx] = t;
        t[0] = (half_t)vv.z; t[1] = (half_t)vv.w; vl2[2 * idx + 1] = t;
    }
    __syncthreads();

    const int n0 = blockIdx.y * 256 + threadIdx.x;      // max 21887, always ok
    const int n1 = n0 + 128;
    const bool ok1 = (n1 < NTOK);

    float qa[16];
    h2 q0h[8], q1h[8];
    ld16_g(P + ((size_t)b * NTOK + n0) * 288 + 96 + h * 16, qa);
    cvt_q(qa, q0h);
    ld16_g(P + ((size_t)b * NTOK + (ok1 ? n1 : n0)) * 288 + 96 + h * 16, qa);
    cvt_q(qa, q1h);

    float a0[16], a1[16];
#pragma unroll
    for (int e = 0; e < 16; e++) { a0[e] = 0.f; a1[e] = 0.f; }
    float l0 = 0.f, l1 = 0.f;

    attn_core2(kl2, vl2, q0h, q1h, a0, a1, l0, l1);

    st16_g(y + ((size_t)b * NTOK + n0) * 96 + h * 16, a0, 1.f / l0);
    if (ok1)
        st16_g(y + ((size_t)b * NTOK + n1) * 96 + h * 16, a1, 1.f / l1);
}

// ---------------------------------------------------------------------------
// K4: branch-2 windowed attention -> y[:, :, 48:96]
// grid 768 = (b,h,win) x 2 query-halves, 128 threads, 2 queries/thread.
// ---------------------------------------------------------------------------
__global__ __launch_bounds__(128) void k_attn2(
    const float* __restrict__ P, float* __restrict__ y)
{
    __shared__ h2 kl2[NSR * 8];
    __shared__ h2 vl2[NSR * 8];
    const int pb = blockIdx.x >> 1, half = blockIdx.x & 1;
    const int b = pb / 192;
    const int rem = pb % 192;
    const int h = rem / 64, win = rem % 64;
    const int wh = win >> 4, ww = (win >> 2) & 3, wd = win & 3;
    const int h0 = wh * 7, w0 = ww * 7, d0 = wd * 7;

    for (int idx = threadIdx.x; idx < NSR * 4; idx += 128) {
        int m = idx >> 2, e4 = idx & 3;
        int a = m / 49, bw = (m / 7) % 7, cw = m % 7;
        int n = (h0 + a) * WD + (w0 + bw) * 28 + (d0 + cw);
        const float* src = P + ((size_t)b * NTOK + n) * 288 + 192 + h * 16 + e4 * 4;
        float4 kv = *(const float4*)src;
        float4 vv = *(const float4*)(src + 48);
        h2 t;
        t[0] = (half_t)kv.x; t[1] = (half_t)kv.y; kl2[2 * idx] = t;
        t[0] = (half_t)kv.z; t[1] = (half_t)kv.w; kl2[2 * idx + 1] = t;
        t[0] = (half_t)vv.x; t[1] = (half_t)vv.y; vl2[2 * idx] = t;
        t[0] = (half_t)vv.z; t[1] = (half_t)vv.w; vl2[2 * idx + 1] = t;
    }
    __syncthreads();

    const int base = half * 172;
    const int qend = half ? NSR : 172;
    const int t0 = base + threadIdx.x;          // always < qend
    const int t1 = t0 + 128;
    const bool ok1 = (t1 < qend);
    const int t1c = ok1 ? t1 : base;

    int a0i = t0 / 49, b0i = (t0 / 7) % 7, c0i = t0 % 7;
    int n0 = (h0 + a0i) * WD + (w0 + b0i) * 28 + (d0 + c0i);
    int a1i = t1c / 49, b1i = (t1c / 7) % 7, c1i = t1c % 7;
    int n1 = (h0 + a1i) * WD + (w0 + b1i) * 28 + (d0 + c1i);

    float qa[16];
    h2 q0h[8], q1h[8];
    ld16_g(P + ((size_t)b * NTOK + n0) * 288 + 144 + h * 16, qa);
    cvt_q(qa, q0h);
    ld16_g(P + ((size_t)b * NTOK + n1) * 288 + 144 + h * 16, qa);
    cvt_q(qa, q1h);

    float a0[16], a1[16];
#pragma unroll
    for (int e = 0; e < 16; e++) { a0[e] = 0.f; a1[e] = 0.f; }
    float l0 = 0.f, l1 = 0.f;

    attn_core2(kl2, vl2, q0h, q1h, a0, a1, l0, l1);

    st16_g(y + ((size_t)b * NTOK + n0) * 96 + 48 + h * 16, a0, 1.f / l0);
    if (ok1)
        st16_g(y + ((size_t)b * NTOK + n1) * 96 + 48 + h * 16, a1, 1.f / l1);
}

// K5: LePE depthwise 3x3x3 conv over t = P[:,0:96]; y += lepe
__global__ __launch_bounds__(256) void k_lepe(
    const float* __restrict__ P, const float* __restrict__ cw,
    const float* __restrict__ cb, float* __restrict__ y)
{
    const int id = blockIdx.x * 256 + threadIdx.x;
    if (id >= BB * NTOK * CC) return;
    const int c = id % 96;
    const int n = (id / 96) % NTOK;
    const int b = id / (96 * NTOK);
    const int h = n / WD, w = (n / 28) % 28, d = n % 28;
    float wv[27];
#pragma unroll
    for (int i = 0; i < 27; i++) wv[i] = cw[c * 27 + i];
    float acc = cb[c];
#pragma unroll
    for (int p = 0; p < 3; p++) {
        int hh = h + p - 1;
        if (hh < 0 || hh >= 28) continue;
#pragma unroll
        for (int q = 0; q < 3; q++) {
            int wwi = w + q - 1;
            if (wwi < 0 || wwi >= 28) continue;
#pragma unroll
            for (int r = 0; r < 3; r++) {
                int dd = d + r - 1;
                if (dd < 0 || dd >= 28) continue;
                int nn = hh * WD + wwi * 28 + dd;
                acc += P[((size_t)b * NTOK + nn) * 288 + c] * wv[p * 9 + q * 3 + r];
            }
        }
    }
    y[id] += acc;
}

// ---------------------------------------------------------------------------
// K6: out = y @ proj_w^T + proj_b  — register-tiled GEMM, 64 tok x 48 j tile
// ---------------------------------------------------------------------------
__global__ __launch_bounds__(192) void k_out(
    const float* __restrict__ y, const float* __restrict__ proj_w,
    const float* __restrict__ proj_b, float* __restrict__ out)
{
    __shared__ float xT[96][68];
    __shared__ float wT[96][52];

    const int base = blockIdx.x * 64;
    const int j0 = blockIdx.y * 48;

    for (int it = threadIdx.x; it < 1536; it += 192) {
        int cq = it % 24, t = it / 24;
        float4 v = *(const float4*)(y + (size_t)(base + t) * 96 + cq * 4);
        xT[cq * 4 + 0][t] = v.x; xT[cq * 4 + 1][t] = v.y;
        xT[cq * 4 + 2][t] = v.z; xT[cq * 4 + 3][t] = v.w;
    }
    for (int it = threadIdx.x; it < 1152; it += 192) {
        int cq = it % 24, jl = it / 24;
        float4 v = *(const float4*)(proj_w + (size_t)(j0 + jl) * 96 + cq * 4);
        wT[cq * 4 + 0][jl] = v.x; wT[cq * 4 + 1][jl] = v.y;
        wT[cq * 4 + 2][jl] = v.z; wT[cq * 4 + 3][jl] = v.w;
    }
    __syncthreads();

    const int tq = threadIdx.x & 15;
    const int jq = threadIdx.x >> 4;
    float acc[4][4];
#pragma unroll
    for (int i = 0; i < 4; i++)
#pragma unroll
        for (int jj = 0; jj < 4; jj++) acc[i][jj] = 0.f;

    for (int c = 0; c < 96; c++) {
        float4 xv = *(const float4*)(&xT[c][tq * 4]);
        float4 wv = *(const float4*)(&wT[c][jq * 4]);
        float xa[4] = {xv.x, xv.y, xv.z, xv.w};
        float wa[4] = {wv.x, wv.y, wv.z, wv.w};
#pragma unroll
        for (int i = 0; i < 4; i++)
#pragma unroll
            for (int jj = 0; jj < 4; jj++) acc[i][jj] += xa[i] * wa[jj];
    }

    float4 bias = *(const float4*)(proj_b + j0 + jq * 4);
#pragma unroll
    for (int i = 0; i < 4; i++) {
        int t = base + tq * 4 + i;
        float4 o = make_float4(acc[i][0] + bias.x, acc[i][1] + bias.y,
                               acc[i][2] + bias.z, acc[i][3] + bias.w);
        *(float4*)(out + (size_t)t * 96 + j0 + jq * 4) = o;
    }
}

extern "C" void kernel_launch(void* const* d_in, const int* in_sizes, int n_in,
                              void* d_out, int out_size, void* d_ws, size_t ws_size,
                              hipStream_t stream) {
    const float* x          = (const float*)d_in[0];
    const float* lepe_lin_w = (const float*)d_in[4];
    const float* lepe_lin_b = (const float*)d_in[5];
    const float* lepe_conv_w= (const float*)d_in[6];
    const float* lepe_conv_b= (const float*)d_in[7];
    const float* sr_w       = (const float*)d_in[8];
    const float* sr_b       = (const float*)d_in[9];
    const float* norm_g     = (const float*)d_in[10];
    const float* norm_b     = (const float*)d_in[11];
    const float* q1_w       = (const float*)d_in[12];
    const float* kv1_w      = (const float*)d_in[13];
    const float* q2_w       = (const float*)d_in[14];
    const float* kv2_w      = (const float*)d_in[15];
    const float* proj_w     = (const float*)d_in[16];
    const float* proj_b     = (const float*)d_in[17];

    float* P   = (float*)d_ws;                        // [B*N][288]
    float* k1  = P + (size_t)BB * NTOK * 288;         // [B][3][343][16]
    float* v1  = k1 + (size_t)BB * 3 * NSR * 16;
    float* y   = v1 + (size_t)BB * 3 * NSR * 16;      // [B*N][96]
    float* pa  = y + (size_t)BB * NTOK * 96;          // [686][16][96]
    float* Wt  = pa + (size_t)NSITE * 16 * 96;        // [1536][96] float4

    k_wt<<<576, 256, 0, stream>>>(sr_w, (float4*)Wt);
    k_proj<<<dim3(686, 6), 192, 0, stream>>>(x, lepe_lin_w, lepe_lin_b, q1_w, q2_w, kv2_w, P);
    k_sr_a<<<dim3(86, 16), 128, 0, stream>>>(x, (const float4*)Wt, pa);
    k_sr_b<<<NSITE, 96, 0, stream>>>(pa, sr_b, norm_g, norm_b, kv1_w, k1, v1);
    k_attn1<<<dim3(6, 86), 128, 0, stream>>>(P, k1, v1, y);
    k_attn2<<<768, 128, 0, stream>>>(P, y);
    k_lepe<<<(BB * NTOK * CC + 255) / 256, 256, 0, stream>>>(P, lepe_conv_w, lepe_conv_b, y);
    k_out<<<dim3(686, 2), 192, 0, stream>>>(y, proj_w, proj_b, (float*)d_out);
}

// Round 8
// 464.293 us; speedup vs baseline: 1.0854x; 1.0854x over previous
//
#include <hip/hip_runtime.h>

#define BB 2
#define NTOK 21952      // 28^3
#define CC 96
#define WD 784          // 28*28
#define NSR 343         // 7^3
#define NSITE 686       // BB*NSR
#define SCALE 0.25f
#define LN_EPS 1e-5f

typedef _Float16 half_t;
typedef __attribute__((ext_vector_type(2))) _Float16 h2;
typedef __attribute__((ext_vector_type(8))) _Float16 h8;
union HU { h8 v; h2 p[4]; };

// ---------------------------------------------------------------------------
// K0: transpose sr_w [96][6144] -> Wt4[1536][96] (float4 over 4 consecutive k)
// ---------------------------------------------------------------------------
__global__ __launch_bounds__(256) void k_wt(
    const float* __restrict__ w, float4* __restrict__ Wt4)
{
    const int id = blockIdx.x * 256 + threadIdx.x;
    if (id >= 96 * 1536) return;
    const int co = id % 96, kbg = id / 96;
    const float4 v = *(const float4*)(w + (size_t)co * 6144 + 4 * kbg);
    Wt4[(size_t)kbg * 96 + co] = v;
}

// ---------------------------------------------------------------------------
// K1: P[token][288] = x @ [lepe_lin | q1 | q2 | kv2]^T  (+ lepe bias on 0:96)
// ---------------------------------------------------------------------------
__global__ __launch_bounds__(192) void k_proj(
    const float* __restrict__ x, const float* __restrict__ lepe_w,
    const float* __restrict__ lepe_b, const float* __restrict__ q1_w,
    const float* __restrict__ q2_w, const float* __restrict__ kv2_w,
    float* __restrict__ P)
{
    __shared__ float xT[96][68];   // [k][t]
    __shared__ float wT[96][52];   // [k][j]

    const int base = blockIdx.x * 64;
    const int j0 = blockIdx.y * 48;

    for (int it = threadIdx.x; it < 1536; it += 192) {
        int cq = it % 24, t = it / 24;
        float4 v = *(const float4*)(x + (size_t)(base + t) * 96 + cq * 4);
        xT[cq * 4 + 0][t] = v.x; xT[cq * 4 + 1][t] = v.y;
        xT[cq * 4 + 2][t] = v.z; xT[cq * 4 + 3][t] = v.w;
    }
    for (int it = threadIdx.x; it < 1152; it += 192) {
        int cq = it % 24, jl = it / 24;
        int jg = j0 + jl;
        const float* wrow;
        if (jg < 96)       wrow = lepe_w + jg * 96;
        else if (jg < 144) wrow = q1_w + (jg - 96) * 96;
        else if (jg < 192) wrow = q2_w + (jg - 144) * 96;
        else               wrow = kv2_w + (jg - 192) * 96;
        float4 v = *(const float4*)(wrow + cq * 4);
        wT[cq * 4 + 0][jl] = v.x; wT[cq * 4 + 1][jl] = v.y;
        wT[cq * 4 + 2][jl] = v.z; wT[cq * 4 + 3][jl] = v.w;
    }
    __syncthreads();

    const int tq = threadIdx.x & 15;
    const int jq = threadIdx.x >> 4;
    float acc[4][4];
#pragma unroll
    for (int i = 0; i < 4; i++)
#pragma unroll
        for (int jj = 0; jj < 4; jj++) acc[i][jj] = 0.f;

    for (int c = 0; c < 96; c++) {
        float4 xv = *(const float4*)(&xT[c][tq * 4]);
        float4 wv = *(const float4*)(&wT[c][jq * 4]);
        float xa[4] = {xv.x, xv.y, xv.z, xv.w};
        float wa[4] = {wv.x, wv.y, wv.z, wv.w};
#pragma unroll
        for (int i = 0; i < 4; i++)
#pragma unroll
            for (int jj = 0; jj < 4; jj++) acc[i][jj] += xa[i] * wa[jj];
    }

    float bias[4];
#pragma unroll
    for (int jj = 0; jj < 4; jj++) {
        int jg = j0 + jq * 4 + jj;
        bias[jj] = (jg < 96) ? lepe_b[jg] : 0.f;
    }
#pragma unroll
    for (int i = 0; i < 4; i++) {
        int t = base + tq * 4 + i;
        float4 o = make_float4(acc[i][0] + bias[0], acc[i][1] + bias[1],
                               acc[i][2] + bias[2], acc[i][3] + bias[3]);
        *(float4*)(P + (size_t)t * 288 + j0 + jq * 4) = o;
    }
}

// ---------------------------------------------------------------------------
// K2a: SR conv split-K GEMM. grid (86 site-groups x 16 k-splits), block 128.
// ---------------------------------------------------------------------------
__global__ __launch_bounds__(128) void k_sr_a(
    const float* __restrict__ x, const float4* __restrict__ Wt4,
    float* __restrict__ pa)
{
    __shared__ float patch[8 * 384];
    const int sg = blockIdx.x, ks = blockIdx.y;
    const int ci0 = ks * 6;

    for (int pr = threadIdx.x; pr < 512; pr += 128) {
        int s = pr >> 6, p = pr & 63;
        int s_g = sg * 8 + s; if (s_g > NSITE - 1) s_g = NSITE - 1;
        int b = s_g / NSR, sloc = s_g % NSR;
        int si = sloc / 49, sj = (sloc / 7) % 7, sk = sloc % 7;
        int a = p >> 4, q = (p >> 2) & 3, r = p & 3;
        int n = (4 * si + a) * WD + (4 * sj + q) * 28 + (4 * sk + r);
        const float2* xp = (const float2*)(x + ((size_t)b * NTOK + n) * 96 + ci0);
        float2 v0 = xp[0], v1 = xp[1], v2 = xp[2];
        int base = s * 384 + p;
        patch[base +   0] = v0.x; patch[base +  64] = v0.y;
        patch[base + 128] = v1.x; patch[base + 192] = v1.y;
        patch[base + 256] = v2.x; patch[base + 320] = v2.y;
    }
    __syncthreads();

    const int co = threadIdx.x;
    if (co >= 96) return;
    float acc[8];
#pragma unroll
    for (int s = 0; s < 8; s++) acc[s] = 0.f;
    const float4* p4 = (const float4*)patch;
    const float4* wb = Wt4 + (size_t)ks * 96 * 96 + co;
    for (int kb = 0; kb < 96; kb++) {
        float4 w = wb[(size_t)kb * 96];
#pragma unroll
        for (int s = 0; s < 8; s++) {
            float4 pv = p4[s * 96 + kb];
            acc[s] += pv.x * w.x + pv.y * w.y + pv.z * w.z + pv.w * w.w;
        }
    }
#pragma unroll
    for (int s = 0; s < 8; s++) {
        int s_g = sg * 8 + s;
        if (s_g < NSITE)
            pa[((size_t)s_g * 16 + ks) * 96 + co] = acc[s];
    }
}

// ---------------------------------------------------------------------------
// K2b: reduce 16 partials + bias + LN + GELU + kv1 -> k1/v1 [B][3][343][16]
// ---------------------------------------------------------------------------
__global__ __launch_bounds__(96) void k_sr_b(
    const float* __restrict__ pa, const float* __restrict__ sr_b,
    const float* __restrict__ norm_g, const float* __restrict__ norm_b,
    const float* __restrict__ kv1_w, float* __restrict__ k1,
    float* __restrict__ v1)
{
    __shared__ float xs_s[96];
    __shared__ float gx[96];
    const int s_g = blockIdx.x;
    const int b = s_g / NSR, s = s_g % NSR;
    const int co = threadIdx.x;

    const float* pp = pa + (size_t)s_g * 16 * 96 + co;
    float acc = sr_b[co];
#pragma unroll
    for (int ks = 0; ks < 16; ks++) acc += pp[ks * 96];
    xs_s[co] = acc;
    __syncthreads();

    float m = 0.f, m2 = 0.f;
    for (int c = 0; c < 96; c++) { float v = xs_s[c]; m += v; m2 += v * v; }
    m *= (1.f / 96.f);
    float var = m2 * (1.f / 96.f) - m * m;
    float t = (acc - m) * rsqrtf(var + LN_EPS) * norm_g[co] + norm_b[co];
    gx[co] = 0.5f * t * (1.f + erff(t * 0.70710678118654752f));
    __syncthreads();

    const float4* w4 = (const float4*)(kv1_w + co * 96);
    const float4* g4 = (const float4*)gx;
    float a2 = 0.f;
#pragma unroll
    for (int c = 0; c < 24; c++) {
        float4 w = w4[c]; float4 g = g4[c];
        a2 += g.x * w.x + g.y * w.y + g.z * w.z + g.w * w.w;
    }
    int pair = co / 48, h = (co % 48) / 16, e = co % 16;
    float* dst = pair ? v1 : k1;
    dst[(((size_t)b * 3 + h) * NSR + s) * 16 + e] = a2;
}

// ---------------------------------------------------------------------------
// helpers
// ---------------------------------------------------------------------------
__device__ __forceinline__ void ld16_g(const float* p, float* o) {
    const float4* p4 = (const float4*)p;
#pragma unroll
    for (int i = 0; i < 4; i++) {
        float4 v = p4[i];
        o[4 * i] = v.x; o[4 * i + 1] = v.y; o[4 * i + 2] = v.z; o[4 * i + 3] = v.w;
    }
}
__device__ __forceinline__ void st16_g(float* p, const float* o, float scl) {
    float4* p4 = (float4*)p;
#pragma unroll
    for (int i = 0; i < 4; i++)
        p4[i] = make_float4(o[4 * i] * scl, o[4 * i + 1] * scl,
                            o[4 * i + 2] * scl, o[4 * i + 3] * scl);
}
__device__ __forceinline__ void cvt_q(const float* qa, h2* qh) {
#pragma unroll
    for (int i = 0; i < 8; i++) {
        h2 t; t[0] = (half_t)qa[2 * i]; t[1] = (half_t)qa[2 * i + 1];
        qh[i] = t;
    }
}

// stage float4 K/V rows into f16 LDS (idx strided by nthr over NSR*4)
__device__ __forceinline__ void stage_f16(
    h2* kl2, h2* vl2, const float4 kv, const float4 vv, int idx)
{
    h2 t;
    t[0] = (half_t)kv.x; t[1] = (half_t)kv.y; kl2[2 * idx] = t;
    t[0] = (half_t)kv.z; t[1] = (half_t)kv.w; kl2[2 * idx + 1] = t;
    t[0] = (half_t)vv.x; t[1] = (half_t)vv.y; vl2[2 * idx] = t;
    t[0] = (half_t)vv.z; t[1] = (half_t)vv.w; vl2[2 * idx + 1] = t;
}

// attention partial: 1 query, keys [k0,k1), K/V f16 in LDS
__device__ __forceinline__ void attn_run(
    const h2* kl2, const h2* vl2, int k0, int k1e, const h2* qh,
    float* a, float& l)
{
    const h8* kp = (const h8*)kl2;
    const h8* vp = (const h8*)vl2;
    for (int m = k0; m < k1e; m++) {
        HU ka, kb, va, vb;
        ka.v = kp[2 * m]; kb.v = kp[2 * m + 1];
        va.v = vp[2 * m]; vb.v = vp[2 * m + 1];
        float s = 0.f;
#pragma unroll
        for (int i = 0; i < 4; i++) {
            s = __builtin_amdgcn_fdot2(qh[i], ka.p[i], s, false);
            s = __builtin_amdgcn_fdot2(qh[4 + i], kb.p[i], s, false);
        }
        float p = __expf(s * SCALE);
        l += p;
#pragma unroll
        for (int i = 0; i < 4; i++) {
            a[2 * i]         += p * (float)va.p[i][0];
            a[2 * i + 1]     += p * (float)va.p[i][1];
            a[8 + 2 * i]     += p * (float)vb.p[i][0];
            a[8 + 2 * i + 1] += p * (float)vb.p[i][1];
        }
    }
}

// ---------------------------------------------------------------------------
// K3: branch-1 SR attention -> y[:, :, 0:48]
// grid (6, 172), 256 threads: 128 queries x 2 key-halves, LDS combine.
// ---------------------------------------------------------------------------
__global__ __launch_bounds__(256) void k_attn1(
    const float* __restrict__ P, const float* __restrict__ k1,
    const float* __restrict__ v1, float* __restrict__ y)
{
    __shared__ h2 kl2[NSR * 8];
    __shared__ h2 vl2[NSR * 8];
    __shared__ float pl[128][17];
    const int bh = blockIdx.x;
    const int b = bh / 3, h = bh % 3;
    const float4* ks = (const float4*)(k1 + (size_t)bh * NSR * 16);
    const float4* vs = (const float4*)(v1 + (size_t)bh * NSR * 16);
    for (int idx = threadIdx.x; idx < NSR * 4; idx += 256)
        stage_f16(kl2, vl2, ks[idx], vs[idx], idx);
    __syncthreads();

    const int khalf = threadIdx.x >> 7;       // 0 or 1
    const int qloc = threadIdx.x & 127;
    const int n0 = blockIdx.y * 128 + qloc;
    const bool ok = (n0 < NTOK);
    const int nq = ok ? n0 : (NTOK - 1);

    float qa[16]; h2 qh[8];
    ld16_g(P + ((size_t)b * NTOK + nq) * 288 + 96 + h * 16, qa);
    cvt_q(qa, qh);

    float a[16];
#pragma unroll
    for (int e = 0; e < 16; e++) a[e] = 0.f;
    float l = 0.f;

    attn_run(kl2, vl2, khalf ? 172 : 0, khalf ? NSR : 172, qh, a, l);

    if (khalf) {
#pragma unroll
        for (int e = 0; e < 16; e++) pl[qloc][e] = a[e];
        pl[qloc][16] = l;
    }
    __syncthreads();
    if (!khalf && ok) {
#pragma unroll
        for (int e = 0; e < 16; e++) a[e] += pl[qloc][e];
        l += pl[qloc][16];
        st16_g(y + ((size_t)b * NTOK + n0) * 96 + h * 16, a, 1.f / l);
    }
}

// ---------------------------------------------------------------------------
// K4: branch-2 windowed attention -> y[:, :, 48:96]
// grid 768 = (b,h,win) x 2 q-halves, 384 threads: 172 q x 2 key-halves.
// ---------------------------------------------------------------------------
__global__ __launch_bounds__(384) void k_attn2(
    const float* __restrict__ P, float* __restrict__ y)
{
    __shared__ h2 kl2[NSR * 8];
    __shared__ h2 vl2[NSR * 8];
    __shared__ float pl[172][17];
    const int pb = blockIdx.x >> 1, qhalf = blockIdx.x & 1;
    const int b = pb / 192;
    const int rem = pb % 192;
    const int h = rem / 64, win = rem % 64;
    const int wh = win >> 4, ww = (win >> 2) & 3, wd = win & 3;
    const int h0 = wh * 7, w0 = ww * 7, d0 = wd * 7;

    for (int idx = threadIdx.x; idx < NSR * 4; idx += 384) {
        int m = idx >> 2, e4 = idx & 3;
        int a = m / 49, bw = (m / 7) % 7, cw = m % 7;
        int n = (h0 + a) * WD + (w0 + bw) * 28 + (d0 + cw);
        const float* src = P + ((size_t)b * NTOK + n) * 288 + 192 + h * 16 + e4 * 4;
        stage_f16(kl2, vl2, *(const float4*)src, *(const float4*)(src + 48), idx);
    }
    __syncthreads();

    const int khalf = (threadIdx.x >= 192) ? 1 : 0;
    const int qloc = khalf ? (threadIdx.x - 192) : threadIdx.x;
    const int q = qhalf * 172 + qloc;
    const bool ok = (qloc < 172) && (q < NSR);
    const int qc = ok ? q : 0;

    int ai = qc / 49, bi = (qc / 7) % 7, ci = qc % 7;
    int n0 = (h0 + ai) * WD + (w0 + bi) * 28 + (d0 + ci);

    float qa[16]; h2 qh[8];
    ld16_g(P + ((size_t)b * NTOK + n0) * 288 + 144 + h * 16, qa);
    cvt_q(qa, qh);

    float a[16];
#pragma unroll
    for (int e = 0; e < 16; e++) a[e] = 0.f;
    float l = 0.f;

    attn_run(kl2, vl2, khalf ? 172 : 0, khalf ? NSR : 172, qh, a, l);

    if (khalf && ok) {
#pragma unroll
        for (int e = 0; e < 16; e++) pl[qloc][e] = a[e];
        pl[qloc][16] = l;
    }
    __syncthreads();
    if (!khalf && ok) {
#pragma unroll
        for (int e = 0; e < 16; e++) a[e] += pl[qloc][e];
        l += pl[qloc][16];
        st16_g(y + ((size_t)b * NTOK + n0) * 96 + 48 + h * 16, a, 1.f / l);
    }
}

// K5: LePE depthwise 3x3x3 conv over t = P[:,0:96]; y += lepe
__global__ __launch_bounds__(256) void k_lepe(
    const float* __restrict__ P, const float* __restrict__ cw,
    const float* __restrict__ cb, float* __restrict__ y)
{
    const int id = blockIdx.x * 256 + threadIdx.x;
    if (id >= BB * NTOK * CC) return;
    const int c = id % 96;
    const int n = (id / 96) % NTOK;
    const int b = id / (96 * NTOK);
    const int h = n / WD, w = (n / 28) % 28, d = n % 28;
    float wv[27];
#pragma unroll
    for (int i = 0; i < 27; i++) wv[i] = cw[c * 27 + i];
    float acc = cb[c];
#pragma unroll
    for (int p = 0; p < 3; p++) {
        int hh = h + p - 1;
        if (hh < 0 || hh >= 28) continue;
#pragma unroll
        for (int q = 0; q < 3; q++) {
            int wwi = w + q - 1;
            if (wwi < 0 || wwi >= 28) continue;
#pragma unroll
            for (int r = 0; r < 3; r++) {
                int dd = d + r - 1;
                if (dd < 0 || dd >= 28) continue;
                int nn = hh * WD + wwi * 28 + dd;
                acc += P[((size_t)b * NTOK + nn) * 288 + c] * wv[p * 9 + q * 3 + r];
            }
        }
    }
    y[id] += acc;
}

// ---------------------------------------------------------------------------
// K6: out = y @ proj_w^T + proj_b  — register-tiled GEMM, 64 tok x 48 j tile
// ---------------------------------------------------------------------------
__global__ __launch_bounds__(192) void k_out(
    const float* __restrict__ y, const float* __restrict__ proj_w,
    const float* __restrict__ proj_b, float* __restrict__ out)
{
    __shared__ float xT[96][68];
    __shared__ float wT[96][52];

    const int base = blockIdx.x * 64;
    const int j0 = blockIdx.y * 48;

    for (int it = threadIdx.x; it < 1536; it += 192) {
        int cq = it % 24, t = it / 24;
        float4 v = *(const float4*)(y + (size_t)(base + t) * 96 + cq * 4);
        xT[cq * 4 + 0][t] = v.x; xT[cq * 4 + 1][t] = v.y;
        xT[cq * 4 + 2][t] = v.z; xT[cq * 4 + 3][t] = v.w;
    }
    for (int it = threadIdx.x; it < 1152; it += 192) {
        int cq = it % 24, jl = it / 24;
        float4 v = *(const float4*)(proj_w + (size_t)(j0 + jl) * 96 + cq * 4);
        wT[cq * 4 + 0][jl] = v.x; wT[cq * 4 + 1][jl] = v.y;
        wT[cq * 4 + 2][jl] = v.z; wT[cq * 4 + 3][jl] = v.w;
    }
    __syncthreads();

    const int tq = threadIdx.x & 15;
    const int jq = threadIdx.x >> 4;
    float acc[4][4];
#pragma unroll
    for (int i = 0; i < 4; i++)
#pragma unroll
        for (int jj = 0; jj < 4; jj++) acc[i][jj] = 0.f;

    for (int c = 0; c < 96; c++) {
        float4 xv = *(const float4*)(&xT[c][tq * 4]);
        float4 wv = *(const float4*)(&wT[c][jq * 4]);
        float xa[4] = {xv.x, xv.y, xv.z, xv.w};
        float wa[4] = {wv.x, wv.y, wv.z, wv.w};
#pragma unroll
        for (int i = 0; i < 4; i++)
#pragma unroll
            for (int jj = 0; jj < 4; jj++) acc[i][jj] += xa[i] * wa[jj];
    }

    float4 bias = *(const float4*)(proj_b + j0 + jq * 4);
#pragma unroll
    for (int i = 0; i < 4; i++) {
        int t = base + tq * 4 + i;
        float4 o = make_float4(acc[i][0] + bias.x, acc[i][1] + bias.y,
                               acc[i][2] + bias.z, acc[i][3] + bias.w);
        *(float4*)(out + (size_t)t * 96 + j0 + jq * 4) = o;
    }
}

extern "C" void kernel_launch(void* const* d_in, const int* in_sizes, int n_in,
                              void* d_out, int out_size, void* d_ws, size_t ws_size,
                              hipStream_t stream) {
    const float* x          = (const float*)d_in[0];
    const float* lepe_lin_w = (const float*)d_in[4];
    const float* lepe_lin_b = (const float*)d_in[5];
    const float* lepe_conv_w= (const float*)d_in[6];
    const float* lepe_conv_b= (const float*)d_in[7];
    const float* sr_w       = (const float*)d_in[8];
    const float* sr_b       = (const float*)d_in[9];
    const float* norm_g     = (const float*)d_in[10];
    const float* norm_b     = (const float*)d_in[11];
    const float* q1_w       = (const float*)d_in[12];
    const float* kv1_w      = (const float*)d_in[13];
    const float* q2_w       = (const float*)d_in[14];
    const float* kv2_w      = (const float*)d_in[15];
    const float* proj_w     = (const float*)d_in[16];
    const float* proj_b     = (const float*)d_in[17];

    float* P   = (float*)d_ws;                        // [B*N][288]
    float* k1  = P + (size_t)BB * NTOK * 288;         // [B][3][343][16]
    float* v1  = k1 + (size_t)BB * 3 * NSR * 16;
    float* y   = v1 + (size_t)BB * 3 * NSR * 16;      // [B*N][96]
    float* pa  = y + (size_t)BB * NTOK * 96;          // [686][16][96]
    float* Wt  = pa + (size_t)NSITE * 16 * 96;        // [1536][96] float4

    k_wt<<<576, 256, 0, stream>>>(sr_w, (float4*)Wt);
    k_proj<<<dim3(686, 6), 192, 0, stream>>>(x, lepe_lin_w, lepe_lin_b, q1_w, q2_w, kv2_w, P);
    k_sr_a<<<dim3(86, 16), 128, 0, stream>>>(x, (const float4*)Wt, pa);
    k_sr_b<<<NSITE, 96, 0, stream>>>(pa, sr_b, norm_g, norm_b, kv1_w, k1, v1);
    k_attn1<<<dim3(6, 172), 256, 0, stream>>>(P, k1, v1, y);
    k_attn2<<<768, 384, 0, stream>>>(P, y);
    k_lepe<<<(BB * NTOK * CC + 255) / 256, 256, 0, stream>>>(P, lepe_conv_w, lepe_conv_b, y);
    k_out<<<dim3(686, 2), 192, 0, stream>>>(y, proj_w, proj_b, (float*)d_out);
}

// Round 9
// 420.459 us; speedup vs baseline: 1.1985x; 1.1043x over previous
//
#include <hip/hip_runtime.h>

#define BB 2
#define NTOK 21952      // 28^3
#define CC 96
#define WD 784          // 28*28
#define NSR 343         // 7^3
#define NSITE 686       // BB*NSR
#define SCALE 0.25f
#define LN_EPS 1e-5f
#define LNB 4116        // k_lepe logical blocks

typedef _Float16 half_t;
typedef __attribute__((ext_vector_type(2))) _Float16 h2;
typedef __attribute__((ext_vector_type(8))) _Float16 h8;
union HU { h8 v; h2 p[4]; };

// ---------------------------------------------------------------------------
// K0: transpose sr_w [96][6144] -> Wt4[1536][96]; also lepe_conv_w -> cwT[27][96]
// ---------------------------------------------------------------------------
__global__ __launch_bounds__(256) void k_wt(
    const float* __restrict__ w, float4* __restrict__ Wt4,
    const float* __restrict__ cw, float* __restrict__ cwT)
{
    const int id = blockIdx.x * 256 + threadIdx.x;
    if (id < 96 * 1536) {
        const int co = id % 96, kbg = id / 96;
        const float4 v = *(const float4*)(w + (size_t)co * 6144 + 4 * kbg);
        Wt4[(size_t)kbg * 96 + co] = v;
    } else if (id < 96 * 1536 + 27 * 96) {
        const int id2 = id - 96 * 1536;
        const int tap = id2 / 96, c = id2 % 96;
        cwT[tap * 96 + c] = cw[c * 27 + tap];
    }
}

// ---------------------------------------------------------------------------
// K1: P[token][288] = x @ [lepe_lin | q1 | q2 | kv2]^T  (+ lepe bias on 0:96)
// ---------------------------------------------------------------------------
__global__ __launch_bounds__(192) void k_proj(
    const float* __restrict__ x, const float* __restrict__ lepe_w,
    const float* __restrict__ lepe_b, const float* __restrict__ q1_w,
    const float* __restrict__ q2_w, const float* __restrict__ kv2_w,
    float* __restrict__ P)
{
    __shared__ float xT[96][68];   // [k][t]
    __shared__ float wT[96][52];   // [k][j]

    const int base = blockIdx.x * 64;
    const int j0 = blockIdx.y * 48;

    for (int it = threadIdx.x; it < 1536; it += 192) {
        int cq = it % 24, t = it / 24;
        float4 v = *(const float4*)(x + (size_t)(base + t) * 96 + cq * 4);
        xT[cq * 4 + 0][t] = v.x; xT[cq * 4 + 1][t] = v.y;
        xT[cq * 4 + 2][t] = v.z; xT[cq * 4 + 3][t] = v.w;
    }
    for (int it = threadIdx.x; it < 1152; it += 192) {
        int cq = it % 24, jl = it / 24;
        int jg = j0 + jl;
        const float* wrow;
        if (jg < 96)       wrow = lepe_w + jg * 96;
        else if (jg < 144) wrow = q1_w + (jg - 96) * 96;
        else if (jg < 192) wrow = q2_w + (jg - 144) * 96;
        else               wrow = kv2_w + (jg - 192) * 96;
        float4 v = *(const float4*)(wrow + cq * 4);
        wT[cq * 4 + 0][jl] = v.x; wT[cq * 4 + 1][jl] = v.y;
        wT[cq * 4 + 2][jl] = v.z; wT[cq * 4 + 3][jl] = v.w;
    }
    __syncthreads();

    const int tq = threadIdx.x & 15;
    const int jq = threadIdx.x >> 4;
    float acc[4][4];
#pragma unroll
    for (int i = 0; i < 4; i++)
#pragma unroll
        for (int jj = 0; jj < 4; jj++) acc[i][jj] = 0.f;

    for (int c = 0; c < 96; c++) {
        float4 xv = *(const float4*)(&xT[c][tq * 4]);
        float4 wv = *(const float4*)(&wT[c][jq * 4]);
        float xa[4] = {xv.x, xv.y, xv.z, xv.w};
        float wa[4] = {wv.x, wv.y, wv.z, wv.w};
#pragma unroll
        for (int i = 0; i < 4; i++)
#pragma unroll
            for (int jj = 0; jj < 4; jj++) acc[i][jj] += xa[i] * wa[jj];
    }

    float bias[4];
#pragma unroll
    for (int jj = 0; jj < 4; jj++) {
        int jg = j0 + jq * 4 + jj;
        bias[jj] = (jg < 96) ? lepe_b[jg] : 0.f;
    }
#pragma unroll
    for (int i = 0; i < 4; i++) {
        int t = base + tq * 4 + i;
        float4 o = make_float4(acc[i][0] + bias[0], acc[i][1] + bias[1],
                               acc[i][2] + bias[2], acc[i][3] + bias[3]);
        *(float4*)(P + (size_t)t * 288 + j0 + jq * 4) = o;
    }
}

// ---------------------------------------------------------------------------
// K2a: SR conv split-K GEMM. grid (86 site-groups x 16 k-splits), block 128.
// ---------------------------------------------------------------------------
__global__ __launch_bounds__(128) void k_sr_a(
    const float* __restrict__ x, const float4* __restrict__ Wt4,
    float* __restrict__ pa)
{
    __shared__ float patch[8 * 384];
    const int sg = blockIdx.x, ks = blockIdx.y;
    const int ci0 = ks * 6;

    for (int pr = threadIdx.x; pr < 512; pr += 128) {
        int s = pr >> 6, p = pr & 63;
        int s_g = sg * 8 + s; if (s_g > NSITE - 1) s_g = NSITE - 1;
        int b = s_g / NSR, sloc = s_g % NSR;
        int si = sloc / 49, sj = (sloc / 7) % 7, sk = sloc % 7;
        int a = p >> 4, q = (p >> 2) & 3, r = p & 3;
        int n = (4 * si + a) * WD + (4 * sj + q) * 28 + (4 * sk + r);
        const float2* xp = (const float2*)(x + ((size_t)b * NTOK + n) * 96 + ci0);
        float2 v0 = xp[0], v1 = xp[1], v2 = xp[2];
        int base = s * 384 + p;
        patch[base +   0] = v0.x; patch[base +  64] = v0.y;
        patch[base + 128] = v1.x; patch[base + 192] = v1.y;
        patch[base + 256] = v2.x; patch[base + 320] = v2.y;
    }
    __syncthreads();

    const int co = threadIdx.x;
    if (co >= 96) return;
    float acc[8];
#pragma unroll
    for (int s = 0; s < 8; s++) acc[s] = 0.f;
    const float4* p4 = (const float4*)patch;
    const float4* wb = Wt4 + (size_t)ks * 96 * 96 + co;
    for (int kb = 0; kb < 96; kb++) {
        float4 w = wb[(size_t)kb * 96];
#pragma unroll
        for (int s = 0; s < 8; s++) {
            float4 pv = p4[s * 96 + kb];
            acc[s] += pv.x * w.x + pv.y * w.y + pv.z * w.z + pv.w * w.w;
        }
    }
#pragma unroll
    for (int s = 0; s < 8; s++) {
        int s_g = sg * 8 + s;
        if (s_g < NSITE)
            pa[((size_t)s_g * 16 + ks) * 96 + co] = acc[s];
    }
}

// ---------------------------------------------------------------------------
// K2b: reduce 16 partials + bias + LN + GELU + kv1 -> k1/v1 [B][3][343][16]
// ---------------------------------------------------------------------------
__global__ __launch_bounds__(96) void k_sr_b(
    const float* __restrict__ pa, const float* __restrict__ sr_b,
    const float* __restrict__ norm_g, const float* __restrict__ norm_b,
    const float* __restrict__ kv1_w, float* __restrict__ k1,
    float* __restrict__ v1)
{
    __shared__ float xs_s[96];
    __shared__ float gx[96];
    const int s_g = blockIdx.x;
    const int b = s_g / NSR, s = s_g % NSR;
    const int co = threadIdx.x;

    const float* pp = pa + (size_t)s_g * 16 * 96 + co;
    float acc = sr_b[co];
#pragma unroll
    for (int ks = 0; ks < 16; ks++) acc += pp[ks * 96];
    xs_s[co] = acc;
    __syncthreads();

    float m = 0.f, m2 = 0.f;
    for (int c = 0; c < 96; c++) { float v = xs_s[c]; m += v; m2 += v * v; }
    m *= (1.f / 96.f);
    float var = m2 * (1.f / 96.f) - m * m;
    float t = (acc - m) * rsqrtf(var + LN_EPS) * norm_g[co] + norm_b[co];
    gx[co] = 0.5f * t * (1.f + erff(t * 0.70710678118654752f));
    __syncthreads();

    const float4* w4 = (const float4*)(kv1_w + co * 96);
    const float4* g4 = (const float4*)gx;
    float a2 = 0.f;
#pragma unroll
    for (int c = 0; c < 24; c++) {
        float4 w = w4[c]; float4 g = g4[c];
        a2 += g.x * w.x + g.y * w.y + g.z * w.z + g.w * w.w;
    }
    int pair = co / 48, h = (co % 48) / 16, e = co % 16;
    float* dst = pair ? v1 : k1;
    dst[(((size_t)b * 3 + h) * NSR + s) * 16 + e] = a2;
}

// ---------------------------------------------------------------------------
// helpers
// ---------------------------------------------------------------------------
__device__ __forceinline__ void ld16_g(const float* p, float* o) {
    const float4* p4 = (const float4*)p;
#pragma unroll
    for (int i = 0; i < 4; i++) {
        float4 v = p4[i];
        o[4 * i] = v.x; o[4 * i + 1] = v.y; o[4 * i + 2] = v.z; o[4 * i + 3] = v.w;
    }
}
__device__ __forceinline__ void st16_g(float* p, const float* o, float scl) {
    float4* p4 = (float4*)p;
#pragma unroll
    for (int i = 0; i < 4; i++)
        p4[i] = make_float4(o[4 * i] * scl, o[4 * i + 1] * scl,
                            o[4 * i + 2] * scl, o[4 * i + 3] * scl);
}
__device__ __forceinline__ void cvt_q(const float* qa, h2* qh) {
#pragma unroll
    for (int i = 0; i < 8; i++) {
        h2 t; t[0] = (half_t)qa[2 * i]; t[1] = (half_t)qa[2 * i + 1];
        qh[i] = t;
    }
}

// stage float4 K/V rows into f16 LDS
__device__ __forceinline__ void stage_f16(
    h2* kl2, h2* vl2, const float4 kv, const float4 vv, int idx)
{
    h2 t;
    t[0] = (half_t)kv.x; t[1] = (half_t)kv.y; kl2[2 * idx] = t;
    t[0] = (half_t)kv.z; t[1] = (half_t)kv.w; kl2[2 * idx + 1] = t;
    t[0] = (half_t)vv.x; t[1] = (half_t)vv.y; vl2[2 * idx] = t;
    t[0] = (half_t)vv.z; t[1] = (half_t)vv.w; vl2[2 * idx + 1] = t;
}

// attention partial: 1 query, keys [k0,k1), K/V f16 in LDS
__device__ __forceinline__ void attn_run(
    const h2* kl2, const h2* vl2, int k0, int k1e, const h2* qh,
    float* a, float& l)
{
    const h8* kp = (const h8*)kl2;
    const h8* vp = (const h8*)vl2;
    for (int m = k0; m < k1e; m++) {
        HU ka, kb, va, vb;
        ka.v = kp[2 * m]; kb.v = kp[2 * m + 1];
        va.v = vp[2 * m]; vb.v = vp[2 * m + 1];
        float s = 0.f;
#pragma unroll
        for (int i = 0; i < 4; i++) {
            s = __builtin_amdgcn_fdot2(qh[i], ka.p[i], s, false);
            s = __builtin_amdgcn_fdot2(qh[4 + i], kb.p[i], s, false);
        }
        float p = __expf(s * SCALE);
        l += p;
#pragma unroll
        for (int i = 0; i < 4; i++) {
            a[2 * i]         += p * (float)va.p[i][0];
            a[2 * i + 1]     += p * (float)va.p[i][1];
            a[8 + 2 * i]     += p * (float)vb.p[i][0];
            a[8 + 2 * i + 1] += p * (float)vb.p[i][1];
        }
    }
}

// ---------------------------------------------------------------------------
// K3: branch-1 SR attention -> y[:, :, 0:48]
// grid (6, 172), 256 threads: 128 queries x 2 key-halves, LDS combine.
// ---------------------------------------------------------------------------
__global__ __launch_bounds__(256) void k_attn1(
    const float* __restrict__ P, const float* __restrict__ k1,
    const float* __restrict__ v1, float* __restrict__ y)
{
    __shared__ h2 kl2[NSR * 8];
    __shared__ h2 vl2[NSR * 8];
    __shared__ float pl[128][17];
    const int bh = blockIdx.x;
    const int b = bh / 3, h = bh % 3;
    const float4* ks = (const float4*)(k1 + (size_t)bh * NSR * 16);
    const float4* vs = (const float4*)(v1 + (size_t)bh * NSR * 16);
    for (int idx = threadIdx.x; idx < NSR * 4; idx += 256)
        stage_f16(kl2, vl2, ks[idx], vs[idx], idx);
    __syncthreads();

    const int khalf = threadIdx.x >> 7;
    const int qloc = threadIdx.x & 127;
    const int n0 = blockIdx.y * 128 + qloc;
    const bool ok = (n0 < NTOK);
    const int nq = ok ? n0 : (NTOK - 1);

    float qa[16]; h2 qh[8];
    ld16_g(P + ((size_t)b * NTOK + nq) * 288 + 96 + h * 16, qa);
    cvt_q(qa, qh);

    float a[16];
#pragma unroll
    for (int e = 0; e < 16; e++) a[e] = 0.f;
    float l = 0.f;

    attn_run(kl2, vl2, khalf ? 172 : 0, khalf ? NSR : 172, qh, a, l);

    if (khalf) {
#pragma unroll
        for (int e = 0; e < 16; e++) pl[qloc][e] = a[e];
        pl[qloc][16] = l;
    }
    __syncthreads();
    if (!khalf && ok) {
#pragma unroll
        for (int e = 0; e < 16; e++) a[e] += pl[qloc][e];
        l += pl[qloc][16];
        st16_g(y + ((size_t)b * NTOK + n0) * 96 + h * 16, a, 1.f / l);
    }
}

// ---------------------------------------------------------------------------
// K4: branch-2 windowed attention -> y[:, :, 48:96]
// grid 768 = (b,h,win) x 2 q-halves, 384 threads: 172 q x 2 key-halves.
// ---------------------------------------------------------------------------
__global__ __launch_bounds__(384) void k_attn2(
    const float* __restrict__ P, float* __restrict__ y)
{
    __shared__ h2 kl2[NSR * 8];
    __shared__ h2 vl2[NSR * 8];
    __shared__ float pl[172][17];
    const int pb = blockIdx.x >> 1, qhalf = blockIdx.x & 1;
    const int b = pb / 192;
    const int rem = pb % 192;
    const int h = rem / 64, win = rem % 64;
    const int wh = win >> 4, ww = (win >> 2) & 3, wd = win & 3;
    const int h0 = wh * 7, w0 = ww * 7, d0 = wd * 7;

    for (int idx = threadIdx.x; idx < NSR * 4; idx += 384) {
        int m = idx >> 2, e4 = idx & 3;
        int a = m / 49, bw = (m / 7) % 7, cw = m % 7;
        int n = (h0 + a) * WD + (w0 + bw) * 28 + (d0 + cw);
        const float* src = P + ((size_t)b * NTOK + n) * 288 + 192 + h * 16 + e4 * 4;
        stage_f16(kl2, vl2, *(const float4*)src, *(const float4*)(src + 48), idx);
    }
    __syncthreads();

    const int khalf = (threadIdx.x >= 192) ? 1 : 0;
    const int qloc = khalf ? (threadIdx.x - 192) : threadIdx.x;
    const int q = qhalf * 172 + qloc;
    const bool ok = (qloc < 172) && (q < NSR);
    const int qc = ok ? q : 0;

    int ai = qc / 49, bi = (qc / 7) % 7, ci = qc % 7;
    int n0 = (h0 + ai) * WD + (w0 + bi) * 28 + (d0 + ci);

    float qa[16]; h2 qh[8];
    ld16_g(P + ((size_t)b * NTOK + n0) * 288 + 144 + h * 16, qa);
    cvt_q(qa, qh);

    float a[16];
#pragma unroll
    for (int e = 0; e < 16; e++) a[e] = 0.f;
    float l = 0.f;

    attn_run(kl2, vl2, khalf ? 172 : 0, khalf ? NSR : 172, qh, a, l);

    if (khalf && ok) {
#pragma unroll
        for (int e = 0; e < 16; e++) pl[qloc][e] = a[e];
        pl[qloc][16] = l;
    }
    __syncthreads();
    if (!khalf && ok) {
#pragma unroll
        for (int e = 0; e < 16; e++) a[e] += pl[qloc][e];
        l += pl[qloc][16];
        st16_g(y + ((size_t)b * NTOK + n0) * 96 + 48 + h * 16, a, 1.f / l);
    }
}

// ---------------------------------------------------------------------------
// K5: LePE depthwise 3x3x3 conv over t = P[:,0:96]; y += lepe
// float4 channel groups + XCD-contiguous swizzle for L2 reuse of the 27 taps.
// ---------------------------------------------------------------------------
__global__ __launch_bounds__(256) void k_lepe(
    const float* __restrict__ P, const float* __restrict__ cwT,
    const float* __restrict__ cb, float* __restrict__ y)
{
    // phys block p -> logical l: XCD (p%8) owns a contiguous chunk of tokens
    const int p = blockIdx.x;
    const int l = (p & 7) * 515 + (p >> 3);
    if (l >= LNB) return;
    const int id = l * 256 + threadIdx.x;          // < 4116*256 = BB*NTOK*24 exactly
    const int g4 = (id % 24) * 4;                  // channel quad
    const int nl = id / 24;                        // b*NTOK + n
    const int n = nl % NTOK;
    const int h = n / WD, w = (n / 28) % 28, d = n % 28;
    const float* Pb = P + (size_t)(nl - n) * 288;  // batch base

    float4 acc = *(const float4*)(cb + g4);
#pragma unroll
    for (int tap = 0; tap < 27; tap++) {
        const int dh = tap / 9 - 1, dw = (tap / 3) % 3 - 1, dd = tap % 3 - 1;
        const int hh = h + dh, ww = w + dw, d2 = d + dd;
        const bool v = ((unsigned)hh < 28u) & ((unsigned)ww < 28u) & ((unsigned)d2 < 28u);
        const int nn = v ? (hh * WD + ww * 28 + d2) : n;
        const float m = v ? 1.f : 0.f;
        float4 pv = *(const float4*)(Pb + (size_t)nn * 288 + g4);
        float4 wv = *(const float4*)(cwT + tap * 96 + g4);
        acc.x += pv.x * (wv.x * m);
        acc.y += pv.y * (wv.y * m);
        acc.z += pv.z * (wv.z * m);
        acc.w += pv.w * (wv.w * m);
    }
    float4* yp = (float4*)(y + (size_t)nl * 96 + g4);
    float4 cur = *yp;
    cur.x += acc.x; cur.y += acc.y; cur.z += acc.z; cur.w += acc.w;
    *yp = cur;
}

// ---------------------------------------------------------------------------
// K6: out = y @ proj_w^T + proj_b  — register-tiled GEMM, 64 tok x 48 j tile
// ---------------------------------------------------------------------------
__global__ __launch_bounds__(192) void k_out(
    const float* __restrict__ y, const float* __restrict__ proj_w,
    const float* __restrict__ proj_b, float* __restrict__ out)
{
    __shared__ float xT[96][68];
    __shared__ float wT[96][52];

    const int base = blockIdx.x * 64;
    const int j0 = blockIdx.y * 48;

    for (int it = threadIdx.x; it < 1536; it += 192) {
        int cq = it % 24, t = it / 24;
        float4 v = *(const float4*)(y + (size_t)(base + t) * 96 + cq * 4);
        xT[cq * 4 + 0][t] = v.x; xT[cq * 4 + 1][t] = v.y;
        xT[cq * 4 + 2][t] = v.z; xT[cq * 4 + 3][t] = v.w;
    }
    for (int it = threadIdx.x; it < 1152; it += 192) {
        int cq = it % 24, jl = it / 24;
        float4 v = *(const float4*)(proj_w + (size_t)(j0 + jl) * 96 + cq * 4);
        wT[cq * 4 + 0][jl] = v.x; wT[cq * 4 + 1][jl] = v.y;
        wT[cq * 4 + 2][jl] = v.z; wT[cq * 4 + 3][jl] = v.w;
    }
    __syncthreads();

    const int tq = threadIdx.x & 15;
    const int jq = threadIdx.x >> 4;
    float acc[4][4];
#pragma unroll
    for (int i = 0; i < 4; i++)
#pragma unroll
        for (int jj = 0; jj < 4; jj++) acc[i][jj] = 0.f;

    for (int c = 0; c < 96; c++) {
        float4 xv = *(const float4*)(&xT[c][tq * 4]);
        float4 wv = *(const float4*)(&wT[c][jq * 4]);
        float xa[4] = {xv.x, xv.y, xv.z, xv.w};
        float wa[4] = {wv.x, wv.y, wv.z, wv.w};
#pragma unroll
        for (int i = 0; i < 4; i++)
#pragma unroll
            for (int jj = 0; jj < 4; jj++) acc[i][jj] += xa[i] * wa[jj];
    }

    float4 bias = *(const float4*)(proj_b + j0 + jq * 4);
#pragma unroll
    for (int i = 0; i < 4; i++) {
        int t = base + tq * 4 + i;
        float4 o = make_float4(acc[i][0] + bias.x, acc[i][1] + bias.y,
                               acc[i][2] + bias.z, acc[i][3] + bias.w);
        *(float4*)(out + (size_t)t * 96 + j0 + jq * 4) = o;
    }
}

extern "C" void kernel_launch(void* const* d_in, const int* in_sizes, int n_in,
                              void* d_out, int out_size, void* d_ws, size_t ws_size,
                              hipStream_t stream) {
    const float* x          = (const float*)d_in[0];
    const float* lepe_lin_w = (const float*)d_in[4];
    const float* lepe_lin_b = (const float*)d_in[5];
    const float* lepe_conv_w= (const float*)d_in[6];
    const float* lepe_conv_b= (const float*)d_in[7];
    const float* sr_w       = (const float*)d_in[8];
    const float* sr_b       = (const float*)d_in[9];
    const float* norm_g     = (const float*)d_in[10];
    const float* norm_b     = (const float*)d_in[11];
    const float* q1_w       = (const float*)d_in[12];
    const float* kv1_w      = (const float*)d_in[13];
    const float* q2_w       = (const float*)d_in[14];
    const float* kv2_w      = (const float*)d_in[15];
    const float* proj_w     = (const float*)d_in[16];
    const float* proj_b     = (const float*)d_in[17];

    float* P   = (float*)d_ws;                        // [B*N][288]
    float* k1  = P + (size_t)BB * NTOK * 288;         // [B][3][343][16]
    float* v1  = k1 + (size_t)BB * 3 * NSR * 16;
    float* y   = v1 + (size_t)BB * 3 * NSR * 16;      // [B*N][96]
    float* pa  = y + (size_t)BB * NTOK * 96;          // [686][16][96]
    float* Wt  = pa + (size_t)NSITE * 16 * 96;        // [1536][96] float4
    float* cwT = Wt + (size_t)1536 * 96 * 4;          // [27][96]

    k_wt<<<587, 256, 0, stream>>>(sr_w, (float4*)Wt, lepe_conv_w, cwT);
    k_proj<<<dim3(686, 6), 192, 0, stream>>>(x, lepe_lin_w, lepe_lin_b, q1_w, q2_w, kv2_w, P);
    k_sr_a<<<dim3(86, 16), 128, 0, stream>>>(x, (const float4*)Wt, pa);
    k_sr_b<<<NSITE, 96, 0, stream>>>(pa, sr_b, norm_g, norm_b, kv1_w, k1, v1);
    k_attn1<<<dim3(6, 172), 256, 0, stream>>>(P, k1, v1, y);
    k_attn2<<<768, 384, 0, stream>>>(P, y);
    k_lepe<<<4120, 256, 0, stream>>>(P, cwT, lepe_conv_b, y);
    k_out<<<dim3(686, 2), 192, 0, stream>>>(y, proj_w, proj_b, (float*)d_out);
}

// Round 11
// 368.094 us; speedup vs baseline: 1.3690x; 1.1423x over previous
//
#include <hip/hip_runtime.h>

#define BB 2
#define NTOK 21952      // 28^3
#define CC 96
#define WD 784          // 28*28
#define NSR 343         // 7^3
#define NSRP 344        // padded (key 343 = zeros)
#define NPAIR 172
#define NSITE 686       // BB*NSR
#define SCALE 0.25f
#define LN_EPS 1e-5f
#define LNB 4116        // k_lepe logical blocks

typedef _Float16 half_t;
typedef __attribute__((ext_vector_type(2))) _Float16 h2;
typedef __attribute__((ext_vector_type(8))) _Float16 h8;
typedef __attribute__((ext_vector_type(2))) __fp16 fp16x2;
union HU { h8 v; h2 p[4]; };

// ---------------------------------------------------------------------------
// K0: transpose sr_w [96][6144] -> Wt4[1536][96]; also lepe_conv_w -> cwT[27][96]
// ---------------------------------------------------------------------------
__global__ __launch_bounds__(256) void k_wt(
    const float* __restrict__ w, float4* __restrict__ Wt4,
    const float* __restrict__ cw, float* __restrict__ cwT)
{
    const int id = blockIdx.x * 256 + threadIdx.x;
    if (id < 96 * 1536) {
        const int co = id % 96, kbg = id / 96;
        const float4 v = *(const float4*)(w + (size_t)co * 6144 + 4 * kbg);
        Wt4[(size_t)kbg * 96 + co] = v;
    } else if (id < 96 * 1536 + 27 * 96) {
        const int id2 = id - 96 * 1536;
        const int tap = id2 / 96, c = id2 % 96;
        cwT[tap * 96 + c] = cw[c * 27 + tap];
    }
}

// ---------------------------------------------------------------------------
// K1: P[token][288] = x @ [lepe_lin | q1 | q2 | kv2]^T  (+ lepe bias on 0:96)
// ---------------------------------------------------------------------------
__global__ __launch_bounds__(192) void k_proj(
    const float* __restrict__ x, const float* __restrict__ lepe_w,
    const float* __restrict__ lepe_b, const float* __restrict__ q1_w,
    const float* __restrict__ q2_w, const float* __restrict__ kv2_w,
    float* __restrict__ P)
{
    __shared__ float xT[96][68];
    __shared__ float wT[96][52];

    const int base = blockIdx.x * 64;
    const int j0 = blockIdx.y * 48;

    for (int it = threadIdx.x; it < 1536; it += 192) {
        int cq = it % 24, t = it / 24;
        float4 v = *(const float4*)(x + (size_t)(base + t) * 96 + cq * 4);
        xT[cq * 4 + 0][t] = v.x; xT[cq * 4 + 1][t] = v.y;
        xT[cq * 4 + 2][t] = v.z; xT[cq * 4 + 3][t] = v.w;
    }
    for (int it = threadIdx.x; it < 1152; it += 192) {
        int cq = it % 24, jl = it / 24;
        int jg = j0 + jl;
        const float* wrow;
        if (jg < 96)       wrow = lepe_w + jg * 96;
        else if (jg < 144) wrow = q1_w + (jg - 96) * 96;
        else if (jg < 192) wrow = q2_w + (jg - 144) * 96;
        else               wrow = kv2_w + (jg - 192) * 96;
        float4 v = *(const float4*)(wrow + cq * 4);
        wT[cq * 4 + 0][jl] = v.x; wT[cq * 4 + 1][jl] = v.y;
        wT[cq * 4 + 2][jl] = v.z; wT[cq * 4 + 3][jl] = v.w;
    }
    __syncthreads();

    const int tq = threadIdx.x & 15;
    const int jq = threadIdx.x >> 4;
    float acc[4][4];
#pragma unroll
    for (int i = 0; i < 4; i++)
#pragma unroll
        for (int jj = 0; jj < 4; jj++) acc[i][jj] = 0.f;

    for (int c = 0; c < 96; c++) {
        float4 xv = *(const float4*)(&xT[c][tq * 4]);
        float4 wv = *(const float4*)(&wT[c][jq * 4]);
        float xa[4] = {xv.x, xv.y, xv.z, xv.w};
        float wa[4] = {wv.x, wv.y, wv.z, wv.w};
#pragma unroll
        for (int i = 0; i < 4; i++)
#pragma unroll
            for (int jj = 0; jj < 4; jj++) acc[i][jj] += xa[i] * wa[jj];
    }

    float bias[4];
#pragma unroll
    for (int jj = 0; jj < 4; jj++) {
        int jg = j0 + jq * 4 + jj;
        bias[jj] = (jg < 96) ? lepe_b[jg] : 0.f;
    }
#pragma unroll
    for (int i = 0; i < 4; i++) {
        int t = base + tq * 4 + i;
        float4 o = make_float4(acc[i][0] + bias[0], acc[i][1] + bias[1],
                               acc[i][2] + bias[2], acc[i][3] + bias[3]);
        *(float4*)(P + (size_t)t * 288 + j0 + jq * 4) = o;
    }
}

// ---------------------------------------------------------------------------
// K2a: SR conv split-K GEMM. grid (86 site-groups x 16 k-splits), block 128.
// ---------------------------------------------------------------------------
__global__ __launch_bounds__(128) void k_sr_a(
    const float* __restrict__ x, const float4* __restrict__ Wt4,
    float* __restrict__ pa)
{
    __shared__ float patch[8 * 384];
    const int sg = blockIdx.x, ks = blockIdx.y;
    const int ci0 = ks * 6;

    for (int pr = threadIdx.x; pr < 512; pr += 128) {
        int s = pr >> 6, p = pr & 63;
        int s_g = sg * 8 + s; if (s_g > NSITE - 1) s_g = NSITE - 1;
        int b = s_g / NSR, sloc = s_g % NSR;
        int si = sloc / 49, sj = (sloc / 7) % 7, sk = sloc % 7;
        int a = p >> 4, q = (p >> 2) & 3, r = p & 3;
        int n = (4 * si + a) * WD + (4 * sj + q) * 28 + (4 * sk + r);
        const float2* xp = (const float2*)(x + ((size_t)b * NTOK + n) * 96 + ci0);
        float2 v0 = xp[0], v1 = xp[1], v2 = xp[2];
        int base = s * 384 + p;
        patch[base +   0] = v0.x; patch[base +  64] = v0.y;
        patch[base + 128] = v1.x; patch[base + 192] = v1.y;
        patch[base + 256] = v2.x; patch[base + 320] = v2.y;
    }
    __syncthreads();

    const int co = threadIdx.x;
    if (co >= 96) return;
    float acc[8];
#pragma unroll
    for (int s = 0; s < 8; s++) acc[s] = 0.f;
    const float4* p4 = (const float4*)patch;
    const float4* wb = Wt4 + (size_t)ks * 96 * 96 + co;
    for (int kb = 0; kb < 96; kb++) {
        float4 w = wb[(size_t)kb * 96];
#pragma unroll
        for (int s = 0; s < 8; s++) {
            float4 pv = p4[s * 96 + kb];
            acc[s] += pv.x * w.x + pv.y * w.y + pv.z * w.z + pv.w * w.w;
        }
    }
#pragma unroll
    for (int s = 0; s < 8; s++) {
        int s_g = sg * 8 + s;
        if (s_g < NSITE)
            pa[((size_t)s_g * 16 + ks) * 96 + co] = acc[s];
    }
}

// ---------------------------------------------------------------------------
// K2b: reduce 16 partials + bias + LN + GELU + kv1 -> k1/v1 [B][3][343][16]
// ---------------------------------------------------------------------------
__global__ __launch_bounds__(96) void k_sr_b(
    const float* __restrict__ pa, const float* __restrict__ sr_b,
    const float* __restrict__ norm_g, const float* __restrict__ norm_b,
    const float* __restrict__ kv1_w, float* __restrict__ k1,
    float* __restrict__ v1)
{
    __shared__ float xs_s[96];
    __shared__ float gx[96];
    const int s_g = blockIdx.x;
    const int b = s_g / NSR, s = s_g % NSR;
    const int co = threadIdx.x;

    const float* pp = pa + (size_t)s_g * 16 * 96 + co;
    float acc = sr_b[co];
#pragma unroll
    for (int ks = 0; ks < 16; ks++) acc += pp[ks * 96];
    xs_s[co] = acc;
    __syncthreads();

    float m = 0.f, m2 = 0.f;
    for (int c = 0; c < 96; c++) { float v = xs_s[c]; m += v; m2 += v * v; }
    m *= (1.f / 96.f);
    float var = m2 * (1.f / 96.f) - m * m;
    float t = (acc - m) * rsqrtf(var + LN_EPS) * norm_g[co] + norm_b[co];
    gx[co] = 0.5f * t * (1.f + erff(t * 0.70710678118654752f));
    __syncthreads();

    const float4* w4 = (const float4*)(kv1_w + co * 96);
    const float4* g4 = (const float4*)gx;
    float a2 = 0.f;
#pragma unroll
    for (int c = 0; c < 24; c++) {
        float4 w = w4[c]; float4 g = g4[c];
        a2 += g.x * w.x + g.y * w.y + g.z * w.z + g.w * w.w;
    }
    int pair = co / 48, h = (co % 48) / 16, e = co % 16;
    float* dst = pair ? v1 : k1;
    dst[(((size_t)b * 3 + h) * NSR + s) * 16 + e] = a2;
}

// ---------------------------------------------------------------------------
// helpers
// ---------------------------------------------------------------------------
__device__ __forceinline__ void ld16_g(const float* p, float* o) {
    const float4* p4 = (const float4*)p;
#pragma unroll
    for (int i = 0; i < 4; i++) {
        float4 v = p4[i];
        o[4 * i] = v.x; o[4 * i + 1] = v.y; o[4 * i + 2] = v.z; o[4 * i + 3] = v.w;
    }
}
__device__ __forceinline__ void st16_g(float* p, const float* o, float scl) {
    float4* p4 = (float4*)p;
#pragma unroll
    for (int i = 0; i < 4; i++)
        p4[i] = make_float4(o[4 * i] * scl, o[4 * i + 1] * scl,
                            o[4 * i + 2] * scl, o[4 * i + 3] * scl);
}
// q -> f16 with SCALE folded in
__device__ __forceinline__ void cvt_qs(const float* qa, h2* qh) {
#pragma unroll
    for (int i = 0; i < 8; i++) {
        h2 t;
        t[0] = (half_t)(qa[2 * i] * SCALE);
        t[1] = (half_t)(qa[2 * i + 1] * SCALE);
        qh[i] = t;
    }
}
// K row (2 float4 = 8 elems) -> 4 h2 at kl2[4*idx..]
__device__ __forceinline__ void stage_k(h2* kl2, const float4 kv, int idx) {
    h2 t;
    t[0] = (half_t)kv.x; t[1] = (half_t)kv.y; kl2[2 * idx] = t;
    t[0] = (half_t)kv.z; t[1] = (half_t)kv.w; kl2[2 * idx + 1] = t;
}
// pack pair-interleaved V: out h8 = (A.x,B.x),(A.y,B.y),(A.z,B.z),(A.w,B.w)
__device__ __forceinline__ h8 packV(const float4 A, const float4 B) {
    HU u;
    u.p[0][0] = (half_t)A.x; u.p[0][1] = (half_t)B.x;
    u.p[1][0] = (half_t)A.y; u.p[1][1] = (half_t)B.y;
    u.p[2][0] = (half_t)A.z; u.p[2][1] = (half_t)B.z;
    u.p[3][0] = (half_t)A.w; u.p[3][1] = (half_t)B.w;
    return u.v;
}

// ---------------------------------------------------------------------------
// paired attention core: pairs [pr0,pr1), q pre-scaled f16, V pair-interleaved.
// per pair: 16 fdot2 (QK) + 2 exp + 1 pkrtz + 16 fdot2 (PV).
// ---------------------------------------------------------------------------
__device__ __forceinline__ void attn_runp(
    const h2* kl2, const h2* vp2, int pr0, int pr1, const h2* qh,
    float* a, float& l)
{
    const h8* kp = (const h8*)kl2;
    const h8* vp = (const h8*)vp2;
    for (int pr = pr0; pr < pr1; pr++) {
        HU ka0, kb0, ka1, kb1, v0, v1, v2m, v3;
        ka0.v = kp[4 * pr];     kb0.v = kp[4 * pr + 1];
        ka1.v = kp[4 * pr + 2]; kb1.v = kp[4 * pr + 3];
        v0.v = vp[4 * pr];      v1.v = vp[4 * pr + 1];
        v2m.v = vp[4 * pr + 2]; v3.v = vp[4 * pr + 3];
        float s0 = 0.f, s1 = 0.f;
#pragma unroll
        for (int i = 0; i < 4; i++) {
            s0 = __builtin_amdgcn_fdot2(qh[i], ka0.p[i], s0, false);
            s0 = __builtin_amdgcn_fdot2(qh[4 + i], kb0.p[i], s0, false);
            s1 = __builtin_amdgcn_fdot2(qh[i], ka1.p[i], s1, false);
            s1 = __builtin_amdgcn_fdot2(qh[4 + i], kb1.p[i], s1, false);
        }
        float p0 = __expf(s0), p1 = __expf(s1);
        l += p0 + p1;
        fp16x2 ppr = __builtin_amdgcn_cvt_pkrtz(p0, p1);
        h2 pp = __builtin_bit_cast(h2, ppr);
#pragma unroll
        for (int i = 0; i < 4; i++) {
            a[i]      = __builtin_amdgcn_fdot2(pp, v0.p[i],  a[i],      false);
            a[4 + i]  = __builtin_amdgcn_fdot2(pp, v1.p[i],  a[4 + i],  false);
            a[8 + i]  = __builtin_amdgcn_fdot2(pp, v2m.p[i], a[8 + i],  false);
            a[12 + i] = __builtin_amdgcn_fdot2(pp, v3.p[i],  a[12 + i], false);
        }
    }
}

// ---------------------------------------------------------------------------
// K3: branch-1 SR attention -> y[:, :, 0:48]
// grid (6, 172), 256 threads: 128 queries x 2 key-halves (paired), LDS combine.
// ---------------------------------------------------------------------------
__global__ __launch_bounds__(256) void k_attn1(
    const float* __restrict__ P, const float* __restrict__ k1,
    const float* __restrict__ v1, float* __restrict__ y)
{
    __shared__ h2 kl2[NSRP * 8];
    __shared__ h2 vp2[NPAIR * 16];
    __shared__ float pl[128][17];
    const int bh = blockIdx.x;
    const int b = bh / 3, h = bh % 3;
    const float4* ks = (const float4*)(k1 + (size_t)bh * NSR * 16);
    const float4* vs = (const float4*)(v1 + (size_t)bh * NSR * 16);
    const float4 z4 = make_float4(0.f, 0.f, 0.f, 0.f);

    for (int idx = threadIdx.x; idx < NSRP * 4; idx += 256) {
        int m = idx >> 2;
        stage_k(kl2, (m < NSR) ? ks[idx] : z4, idx);
    }
    for (int idx = threadIdx.x; idx < NPAIR * 2; idx += 256) {
        int pr = idx >> 1, hf = idx & 1;
        int ma = 2 * pr, mb = ma + 1;
        float4 a0 = vs[ma * 4 + hf * 2], a1 = vs[ma * 4 + hf * 2 + 1];
        float4 b0 = z4, b1 = z4;
        if (mb < NSR) { b0 = vs[mb * 4 + hf * 2]; b1 = vs[mb * 4 + hf * 2 + 1]; }
        h8* vph = (h8*)vp2;
        vph[pr * 4 + hf * 2]     = packV(a0, b0);
        vph[pr * 4 + hf * 2 + 1] = packV(a1, b1);
    }
    __syncthreads();

    const int khalf = threadIdx.x >> 7;
    const int qloc = threadIdx.x & 127;
    const int n0 = blockIdx.y * 128 + qloc;
    const bool ok = (n0 < NTOK);
    const int nq = ok ? n0 : (NTOK - 1);

    float qa[16]; h2 qh[8];
    ld16_g(P + ((size_t)b * NTOK + nq) * 288 + 96 + h * 16, qa);
    cvt_qs(qa, qh);

    float a[16];
#pragma unroll
    for (int e = 0; e < 16; e++) a[e] = 0.f;
    float l = 0.f;

    attn_runp(kl2, vp2, khalf ? 86 : 0, khalf ? NPAIR : 86, qh, a, l);
    if (khalf) l -= 1.f;    // pad key 343: p=exp(0)=1, V=0

    if (khalf) {
#pragma unroll
        for (int e = 0; e < 16; e++) pl[qloc][e] = a[e];
        pl[qloc][16] = l;
    }
    __syncthreads();
    if (!khalf && ok) {
#pragma unroll
        for (int e = 0; e < 16; e++) a[e] += pl[qloc][e];
        l += pl[qloc][16];
        st16_g(y + ((size_t)b * NTOK + n0) * 96 + h * 16, a, 1.f / l);
    }
}

// ---------------------------------------------------------------------------
// K4: branch-2 windowed attention -> y[:, :, 48:96]
// grid 768 = (b,h,win) x 2 q-halves, 384 threads: 172 q x 2 key-halves (paired).
// ---------------------------------------------------------------------------
__global__ __launch_bounds__(384) void k_attn2(
    const float* __restrict__ P, float* __restrict__ y)
{
    __shared__ h2 kl2[NSRP * 8];
    __shared__ h2 vp2[NPAIR * 16];
    __shared__ float pl[172][17];
    const int pb = blockIdx.x >> 1, qhalf = blockIdx.x & 1;
    const int b = pb / 192;
    const int rem = pb % 192;
    const int h = rem / 64, win = rem % 64;
    const int wh = win >> 4, ww = (win >> 2) & 3, wd = win & 3;
    const int h0 = wh * 7, w0 = ww * 7, d0 = wd * 7;
    const float4 z4 = make_float4(0.f, 0.f, 0.f, 0.f);

    for (int idx = threadIdx.x; idx < NSRP * 4; idx += 384) {
        int m = idx >> 2, e4 = idx & 3;
        float4 kv = z4;
        if (m < NSR) {
            int a = m / 49, bw = (m / 7) % 7, cw = m % 7;
            int n = (h0 + a) * WD + (w0 + bw) * 28 + (d0 + cw);
            kv = *(const float4*)(P + ((size_t)b * NTOK + n) * 288 + 192 + h * 16 + e4 * 4);
        }
        stage_k(kl2, kv, idx);
    }
    for (int idx = threadIdx.x; idx < NPAIR * 2; idx += 384) {
        int pr = idx >> 1, hf = idx & 1;
        int ma = 2 * pr, mb = ma + 1;
        int aa = ma / 49, ab = (ma / 7) % 7, ac = ma % 7;
        int na = (h0 + aa) * WD + (w0 + ab) * 28 + (d0 + ac);
        const float* sa = P + ((size_t)b * NTOK + na) * 288 + 240 + h * 16 + hf * 8;
        float4 a0 = *(const float4*)sa, a1 = *(const float4*)(sa + 4);
        float4 b0 = z4, b1 = z4;
        if (mb < NSR) {
            int ba = mb / 49, bbw = (mb / 7) % 7, bc = mb % 7;
            int nb = (h0 + ba) * WD + (w0 + bbw) * 28 + (d0 + bc);
            const float* sb = P + ((size_t)b * NTOK + nb) * 288 + 240 + h * 16 + hf * 8;
            b0 = *(const float4*)sb; b1 = *(const float4*)(sb + 4);
        }
        h8* vph = (h8*)vp2;
        vph[pr * 4 + hf * 2]     = packV(a0, b0);
        vph[pr * 4 + hf * 2 + 1] = packV(a1, b1);
    }
    __syncthreads();

    const int khalf = (threadIdx.x >= 192) ? 1 : 0;
    const int qloc = khalf ? (threadIdx.x - 192) : threadIdx.x;
    const int q = qhalf * 172 + qloc;
    const bool ok = (qloc < 172) && (q < NSR);
    const int qc = ok ? q : 0;

    int ai = qc / 49, bi = (qc / 7) % 7, ci = qc % 7;
    int n0 = (h0 + ai) * WD + (w0 + bi) * 28 + (d0 + ci);

    float qa[16]; h2 qh[8];
    ld16_g(P + ((size_t)b * NTOK + n0) * 288 + 144 + h * 16, qa);
    cvt_qs(qa, qh);

    float a[16];
#pragma unroll
    for (int e = 0; e < 16; e++) a[e] = 0.f;
    float l = 0.f;

    attn_runp(kl2, vp2, khalf ? 86 : 0, khalf ? NPAIR : 86, qh, a, l);
    if (khalf) l -= 1.f;    // pad key 343

    if (khalf && ok) {
#pragma unroll
        for (int e = 0; e < 16; e++) pl[qloc][e] = a[e];
        pl[qloc][16] = l;
    }
    __syncthreads();
    if (!khalf && ok) {
#pragma unroll
        for (int e = 0; e < 16; e++) a[e] += pl[qloc][e];
        l += pl[qloc][16];
        st16_g(y + ((size_t)b * NTOK + n0) * 96 + 48 + h * 16, a, 1.f / l);
    }
}

// ---------------------------------------------------------------------------
// K5: LePE depthwise 3x3x3 conv over t = P[:,0:96]; y += lepe
// ---------------------------------------------------------------------------
__global__ __launch_bounds__(256) void k_lepe(
    const float* __restrict__ P, const float* __restrict__ cwT,
    const float* __restrict__ cb, float* __restrict__ y)
{
    const int p = blockIdx.x;
    const int l = (p & 7) * 515 + (p >> 3);
    if (l >= LNB) return;
    const int id = l * 256 + threadIdx.x;
    const int g4 = (id % 24) * 4;
    const int nl = id / 24;
    const int n = nl % NTOK;
    const int h = n / WD, w = (n / 28) % 28, d = n % 28;
    const float* Pb = P + (size_t)(nl - n) * 288;

    float4 acc = *(const float4*)(cb + g4);
#pragma unroll
    for (int tap = 0; tap < 27; tap++) {
        const int dh = tap / 9 - 1, dw = (tap / 3) % 3 - 1, dd = tap % 3 - 1;
        const int hh = h + dh, ww = w + dw, d2 = d + dd;
        const bool v = ((unsigned)hh < 28u) & ((unsigned)ww < 28u) & ((unsigned)d2 < 28u);
        const int nn = v ? (hh * WD + ww * 28 + d2) : n;
        const float m = v ? 1.f : 0.f;
        float4 pv = *(const float4*)(Pb + (size_t)nn * 288 + g4);
        float4 wv = *(const float4*)(cwT + tap * 96 + g4);
        acc.x += pv.x * (wv.x * m);
        acc.y += pv.y * (wv.y * m);
        acc.z += pv.z * (wv.z * m);
        acc.w += pv.w * (wv.w * m);
    }
    float4* yp = (float4*)(y + (size_t)nl * 96 + g4);
    float4 cur = *yp;
    cur.x += acc.x; cur.y += acc.y; cur.z += acc.z; cur.w += acc.w;
    *yp = cur;
}

// ---------------------------------------------------------------------------
// K6: out = y @ proj_w^T + proj_b  — register-tiled GEMM, 64 tok x 48 j tile
// ---------------------------------------------------------------------------
__global__ __launch_bounds__(192) void k_out(
    const float* __restrict__ y, const float* __restrict__ proj_w,
    const float* __restrict__ proj_b, float* __restrict__ out)
{
    __shared__ float xT[96][68];
    __shared__ float wT[96][52];

    const int base = blockIdx.x * 64;
    const int j0 = blockIdx.y * 48;

    for (int it = threadIdx.x; it < 1536; it += 192) {
        int cq = it % 24, t = it / 24;
        float4 v = *(const float4*)(y + (size_t)(base + t) * 96 + cq * 4);
        xT[cq * 4 + 0][t] = v.x; xT[cq * 4 + 1][t] = v.y;
        xT[cq * 4 + 2][t] = v.z; xT[cq * 4 + 3][t] = v.w;
    }
    for (int it = threadIdx.x; it < 1152; it += 192) {
        int cq = it % 24, jl = it / 24;
        float4 v = *(const float4*)(proj_w + (size_t)(j0 + jl) * 96 + cq * 4);
        wT[cq * 4 + 0][jl] = v.x; wT[cq * 4 + 1][jl] = v.y;
        wT[cq * 4 + 2][jl] = v.z; wT[cq * 4 + 3][jl] = v.w;
    }
    __syncthreads();

    const int tq = threadIdx.x & 15;
    const int jq = threadIdx.x >> 4;
    float acc[4][4];
#pragma unroll
    for (int i = 0; i < 4; i++)
#pragma unroll
        for (int jj = 0; jj < 4; jj++) acc[i][jj] = 0.f;

    for (int c = 0; c < 96; c++) {
        float4 xv = *(const float4*)(&xT[c][tq * 4]);
        float4 wv = *(const float4*)(&wT[c][jq * 4]);
        float xa[4] = {xv.x, xv.y, xv.z, xv.w};
        float wa[4] = {wv.x, wv.y, wv.z, wv.w};
#pragma unroll
        for (int i = 0; i < 4; i++)
#pragma unroll
            for (int jj = 0; jj < 4; jj++) acc[i][jj] += xa[i] * wa[jj];
    }

    float4 bias = *(const float4*)(proj_b + j0 + jq * 4);
#pragma unroll
    for (int i = 0; i < 4; i++) {
        int t = base + tq * 4 + i;
        float4 o = make_float4(acc[i][0] + bias.x, acc[i][1] + bias.y,
                               acc[i][2] + bias.z, acc[i][3] + bias.w);
        *(float4*)(out + (size_t)t * 96 + j0 + jq * 4) = o;
    }
}

extern "C" void kernel_launch(void* const* d_in, const int* in_sizes, int n_in,
                              void* d_out, int out_size, void* d_ws, size_t ws_size,
                              hipStream_t stream) {
    const float* x          = (const float*)d_in[0];
    const float* lepe_lin_w = (const float*)d_in[4];
    const float* lepe_lin_b = (const float*)d_in[5];
    const float* lepe_conv_w= (const float*)d_in[6];
    const float* lepe_conv_b= (const float*)d_in[7];
    const float* sr_w       = (const float*)d_in[8];
    const float* sr_b       = (const float*)d_in[9];
    const float* norm_g     = (const float*)d_in[10];
    const float* norm_b     = (const float*)d_in[11];
    const float* q1_w       = (const float*)d_in[12];
    const float* kv1_w      = (const float*)d_in[13];
    const float* q2_w       = (const float*)d_in[14];
    const float* kv2_w      = (const float*)d_in[15];
    const float* proj_w     = (const float*)d_in[16];
    const float* proj_b     = (const float*)d_in[17];

    float* P   = (float*)d_ws;                        // [B*N][288]
    float* k1  = P + (size_t)BB * NTOK * 288;         // [B][3][343][16]
    float* v1  = k1 + (size_t)BB * 3 * NSR * 16;
    float* y   = v1 + (size_t)BB * 3 * NSR * 16;      // [B*N][96]
    float* pa  = y + (size_t)BB * NTOK * 96;          // [686][16][96]
    float* Wt  = pa + (size_t)NSITE * 16 * 96;        // [1536][96] float4
    float* cwT = Wt + (size_t)1536 * 96 * 4;          // [27][96]

    k_wt<<<587, 256, 0, stream>>>(sr_w, (float4*)Wt, lepe_conv_w, cwT);
    k_proj<<<dim3(686, 6), 192, 0, stream>>>(x, lepe_lin_w, lepe_lin_b, q1_w, q2_w, kv2_w, P);
    k_sr_a<<<dim3(86, 16), 128, 0, stream>>>(x, (const float4*)Wt, pa);
    k_sr_b<<<NSITE, 96, 0, stream>>>(pa, sr_b, norm_g, norm_b, kv1_w, k1, v1);
    k_attn1<<<dim3(6, 172), 256, 0, stream>>>(P, k1, v1, y);
    k_attn2<<<768, 384, 0, stream>>>(P, y);
    k_lepe<<<4120, 256, 0, stream>>>(P, cwT, lepe_conv_b, y);
    k_out<<<dim3(686, 2), 192, 0, stream>>>(y, proj_w, proj_b, (float*)d_out);
}

// Round 12
// 362.575 us; speedup vs baseline: 1.3899x; 1.0152x over previous
//
#include <hip/hip_runtime.h>

#define BB 2
#define NTOK 21952      // 28^3
#define CC 96
#define WD 784          // 28*28
#define NSR 343         // 7^3
#define NSRP 344        // padded (key 343 = zeros)
#define NPAIR 172
#define NSITE 686       // BB*NSR
#define SCALE 0.25f
#define LN_EPS 1e-5f
#define LNB 4116        // k_lepe logical blocks

typedef _Float16 half_t;
typedef __attribute__((ext_vector_type(2))) _Float16 h2;
typedef __attribute__((ext_vector_type(8))) _Float16 h8;
typedef __attribute__((ext_vector_type(2))) __fp16 fp16x2;
union HU { h8 v; h2 p[4]; };

// ---------------------------------------------------------------------------
// K0: transpose sr_w [96][6144] -> Wt4[1536][96]; also lepe_conv_w -> cwT[27][96]
// ---------------------------------------------------------------------------
__global__ __launch_bounds__(256) void k_wt(
    const float* __restrict__ w, float4* __restrict__ Wt4,
    const float* __restrict__ cw, float* __restrict__ cwT)
{
    const int id = blockIdx.x * 256 + threadIdx.x;
    if (id < 96 * 1536) {
        const int co = id % 96, kbg = id / 96;
        const float4 v = *(const float4*)(w + (size_t)co * 6144 + 4 * kbg);
        Wt4[(size_t)kbg * 96 + co] = v;
    } else if (id < 96 * 1536 + 27 * 96) {
        const int id2 = id - 96 * 1536;
        const int tap = id2 / 96, c = id2 % 96;
        cwT[tap * 96 + c] = cw[c * 27 + tap];
    }
}

// ---------------------------------------------------------------------------
// K1: P[token][288] = x @ [lepe_lin | q1 | q2 | kv2]^T  (+ lepe bias on 0:96)
// staging mapping: wave-lanes walk t (tokens) -> conflict-free LDS writes.
// ---------------------------------------------------------------------------
__global__ __launch_bounds__(192) void k_proj(
    const float* __restrict__ x, const float* __restrict__ lepe_w,
    const float* __restrict__ lepe_b, const float* __restrict__ q1_w,
    const float* __restrict__ q2_w, const float* __restrict__ kv2_w,
    float* __restrict__ P)
{
    __shared__ float xT[96][68];
    __shared__ float wT[96][52];

    const int base = blockIdx.x * 64;
    const int j0 = blockIdx.y * 48;

    for (int it = threadIdx.x; it < 1536; it += 192) {
        int t = it & 63, cq = it >> 6;           // lanes share cq, walk t
        float4 v = *(const float4*)(x + (size_t)(base + t) * 96 + cq * 4);
        xT[cq * 4 + 0][t] = v.x; xT[cq * 4 + 1][t] = v.y;
        xT[cq * 4 + 2][t] = v.z; xT[cq * 4 + 3][t] = v.w;
    }
    for (int it = threadIdx.x; it < 1152; it += 192) {
        int jl = it % 48, cq = it / 48;          // lanes walk jl
        int jg = j0 + jl;
        const float* wrow;
        if (jg < 96)       wrow = lepe_w + jg * 96;
        else if (jg < 144) wrow = q1_w + (jg - 96) * 96;
        else if (jg < 192) wrow = q2_w + (jg - 144) * 96;
        else               wrow = kv2_w + (jg - 192) * 96;
        float4 v = *(const float4*)(wrow + cq * 4);
        wT[cq * 4 + 0][jl] = v.x; wT[cq * 4 + 1][jl] = v.y;
        wT[cq * 4 + 2][jl] = v.z; wT[cq * 4 + 3][jl] = v.w;
    }
    __syncthreads();

    const int tq = threadIdx.x & 15;
    const int jq = threadIdx.x >> 4;
    float acc[4][4];
#pragma unroll
    for (int i = 0; i < 4; i++)
#pragma unroll
        for (int jj = 0; jj < 4; jj++) acc[i][jj] = 0.f;

    for (int c = 0; c < 96; c++) {
        float4 xv = *(const float4*)(&xT[c][tq * 4]);
        float4 wv = *(const float4*)(&wT[c][jq * 4]);
        float xa[4] = {xv.x, xv.y, xv.z, xv.w};
        float wa[4] = {wv.x, wv.y, wv.z, wv.w};
#pragma unroll
        for (int i = 0; i < 4; i++)
#pragma unroll
            for (int jj = 0; jj < 4; jj++) acc[i][jj] += xa[i] * wa[jj];
    }

    float bias[4];
#pragma unroll
    for (int jj = 0; jj < 4; jj++) {
        int jg = j0 + jq * 4 + jj;
        bias[jj] = (jg < 96) ? lepe_b[jg] : 0.f;
    }
#pragma unroll
    for (int i = 0; i < 4; i++) {
        int t = base + tq * 4 + i;
        float4 o = make_float4(acc[i][0] + bias[0], acc[i][1] + bias[1],
                               acc[i][2] + bias[2], acc[i][3] + bias[3]);
        *(float4*)(P + (size_t)t * 288 + j0 + jq * 4) = o;
    }
}

// ---------------------------------------------------------------------------
// K2a: SR conv split-K GEMM. grid (86 site-groups x 16 k-splits), block 128.
// ---------------------------------------------------------------------------
__global__ __launch_bounds__(128) void k_sr_a(
    const float* __restrict__ x, const float4* __restrict__ Wt4,
    float* __restrict__ pa)
{
    __shared__ float patch[8 * 384];
    const int sg = blockIdx.x, ks = blockIdx.y;
    const int ci0 = ks * 6;

    for (int pr = threadIdx.x; pr < 512; pr += 128) {
        int s = pr >> 6, p = pr & 63;
        int s_g = sg * 8 + s; if (s_g > NSITE - 1) s_g = NSITE - 1;
        int b = s_g / NSR, sloc = s_g % NSR;
        int si = sloc / 49, sj = (sloc / 7) % 7, sk = sloc % 7;
        int a = p >> 4, q = (p >> 2) & 3, r = p & 3;
        int n = (4 * si + a) * WD + (4 * sj + q) * 28 + (4 * sk + r);
        const float2* xp = (const float2*)(x + ((size_t)b * NTOK + n) * 96 + ci0);
        float2 v0 = xp[0], v1 = xp[1], v2 = xp[2];
        int base = s * 384 + p;
        patch[base +   0] = v0.x; patch[base +  64] = v0.y;
        patch[base + 128] = v1.x; patch[base + 192] = v1.y;
        patch[base + 256] = v2.x; patch[base + 320] = v2.y;
    }
    __syncthreads();

    const int co = threadIdx.x;
    if (co >= 96) return;
    float acc[8];
#pragma unroll
    for (int s = 0; s < 8; s++) acc[s] = 0.f;
    const float4* p4 = (const float4*)patch;
    const float4* wb = Wt4 + (size_t)ks * 96 * 96 + co;
    for (int kb = 0; kb < 96; kb++) {
        float4 w = wb[(size_t)kb * 96];
#pragma unroll
        for (int s = 0; s < 8; s++) {
            float4 pv = p4[s * 96 + kb];
            acc[s] += pv.x * w.x + pv.y * w.y + pv.z * w.z + pv.w * w.w;
        }
    }
#pragma unroll
    for (int s = 0; s < 8; s++) {
        int s_g = sg * 8 + s;
        if (s_g < NSITE)
            pa[((size_t)s_g * 16 + ks) * 96 + co] = acc[s];
    }
}

// ---------------------------------------------------------------------------
// K2b: reduce 16 partials + bias + LN + GELU + kv1 -> k1/v1 [B][3][343][16]
// ---------------------------------------------------------------------------
__global__ __launch_bounds__(96) void k_sr_b(
    const float* __restrict__ pa, const float* __restrict__ sr_b,
    const float* __restrict__ norm_g, const float* __restrict__ norm_b,
    const float* __restrict__ kv1_w, float* __restrict__ k1,
    float* __restrict__ v1)
{
    __shared__ float xs_s[96];
    __shared__ float gx[96];
    const int s_g = blockIdx.x;
    const int b = s_g / NSR, s = s_g % NSR;
    const int co = threadIdx.x;

    const float* pp = pa + (size_t)s_g * 16 * 96 + co;
    float acc = sr_b[co];
#pragma unroll
    for (int ks = 0; ks < 16; ks++) acc += pp[ks * 96];
    xs_s[co] = acc;
    __syncthreads();

    float m = 0.f, m2 = 0.f;
    for (int c = 0; c < 96; c++) { float v = xs_s[c]; m += v; m2 += v * v; }
    m *= (1.f / 96.f);
    float var = m2 * (1.f / 96.f) - m * m;
    float t = (acc - m) * rsqrtf(var + LN_EPS) * norm_g[co] + norm_b[co];
    gx[co] = 0.5f * t * (1.f + erff(t * 0.70710678118654752f));
    __syncthreads();

    const float4* w4 = (const float4*)(kv1_w + co * 96);
    const float4* g4 = (const float4*)gx;
    float a2 = 0.f;
#pragma unroll
    for (int c = 0; c < 24; c++) {
        float4 w = w4[c]; float4 g = g4[c];
        a2 += g.x * w.x + g.y * w.y + g.z * w.z + g.w * w.w;
    }
    int pair = co / 48, h = (co % 48) / 16, e = co % 16;
    float* dst = pair ? v1 : k1;
    dst[(((size_t)b * 3 + h) * NSR + s) * 16 + e] = a2;
}

// ---------------------------------------------------------------------------
// helpers
// ---------------------------------------------------------------------------
__device__ __forceinline__ void ld16_g(const float* p, float* o) {
    const float4* p4 = (const float4*)p;
#pragma unroll
    for (int i = 0; i < 4; i++) {
        float4 v = p4[i];
        o[4 * i] = v.x; o[4 * i + 1] = v.y; o[4 * i + 2] = v.z; o[4 * i + 3] = v.w;
    }
}
__device__ __forceinline__ void st16_g(float* p, const float* o, float scl) {
    float4* p4 = (float4*)p;
#pragma unroll
    for (int i = 0; i < 4; i++)
        p4[i] = make_float4(o[4 * i] * scl, o[4 * i + 1] * scl,
                            o[4 * i + 2] * scl, o[4 * i + 3] * scl);
}
// q -> f16 with SCALE folded in
__device__ __forceinline__ void cvt_qs(const float* qa, h2* qh) {
#pragma unroll
    for (int i = 0; i < 8; i++) {
        h2 t;
        t[0] = (half_t)(qa[2 * i] * SCALE);
        t[1] = (half_t)(qa[2 * i + 1] * SCALE);
        qh[i] = t;
    }
}
// K row (2 float4 = 8 elems) -> 4 h2 at kl2[4*idx..]
__device__ __forceinline__ void stage_k(h2* kl2, const float4 kv, int idx) {
    h2 t;
    t[0] = (half_t)kv.x; t[1] = (half_t)kv.y; kl2[2 * idx] = t;
    t[0] = (half_t)kv.z; t[1] = (half_t)kv.w; kl2[2 * idx + 1] = t;
}
// pack pair-interleaved V: out h8 = (A.x,B.x),(A.y,B.y),(A.z,B.z),(A.w,B.w)
__device__ __forceinline__ h8 packV(const float4 A, const float4 B) {
    HU u;
    u.p[0][0] = (half_t)A.x; u.p[0][1] = (half_t)B.x;
    u.p[1][0] = (half_t)A.y; u.p[1][1] = (half_t)B.y;
    u.p[2][0] = (half_t)A.z; u.p[2][1] = (half_t)B.z;
    u.p[3][0] = (half_t)A.w; u.p[3][1] = (half_t)B.w;
    return u.v;
}

// ---------------------------------------------------------------------------
// paired attention core: pairs [pr0,pr1), q pre-scaled f16, V pair-interleaved.
// ---------------------------------------------------------------------------
__device__ __forceinline__ void attn_runp(
    const h2* kl2, const h2* vp2, int pr0, int pr1, const h2* qh,
    float* a, float& l)
{
    const h8* kp = (const h8*)kl2;
    const h8* vp = (const h8*)vp2;
    for (int pr = pr0; pr < pr1; pr++) {
        HU ka0, kb0, ka1, kb1, v0, v1, v2m, v3;
        ka0.v = kp[4 * pr];     kb0.v = kp[4 * pr + 1];
        ka1.v = kp[4 * pr + 2]; kb1.v = kp[4 * pr + 3];
        v0.v = vp[4 * pr];      v1.v = vp[4 * pr + 1];
        v2m.v = vp[4 * pr + 2]; v3.v = vp[4 * pr + 3];
        float s0 = 0.f, s1 = 0.f;
#pragma unroll
        for (int i = 0; i < 4; i++) {
            s0 = __builtin_amdgcn_fdot2(qh[i], ka0.p[i], s0, false);
            s0 = __builtin_amdgcn_fdot2(qh[4 + i], kb0.p[i], s0, false);
            s1 = __builtin_amdgcn_fdot2(qh[i], ka1.p[i], s1, false);
            s1 = __builtin_amdgcn_fdot2(qh[4 + i], kb1.p[i], s1, false);
        }
        float p0 = __expf(s0), p1 = __expf(s1);
        l += p0 + p1;
        fp16x2 ppr = __builtin_amdgcn_cvt_pkrtz(p0, p1);
        h2 pp = __builtin_bit_cast(h2, ppr);
#pragma unroll
        for (int i = 0; i < 4; i++) {
            a[i]      = __builtin_amdgcn_fdot2(pp, v0.p[i],  a[i],      false);
            a[4 + i]  = __builtin_amdgcn_fdot2(pp, v1.p[i],  a[4 + i],  false);
            a[8 + i]  = __builtin_amdgcn_fdot2(pp, v2m.p[i], a[8 + i],  false);
            a[12 + i] = __builtin_amdgcn_fdot2(pp, v3.p[i],  a[12 + i], false);
        }
    }
}

// ---------------------------------------------------------------------------
// K3: branch-1 SR attention -> y[:, :, 0:48]
// grid (6, 172), 256 threads: 128 queries x 2 key-halves (paired), LDS combine.
// ---------------------------------------------------------------------------
__global__ __launch_bounds__(256) void k_attn1(
    const float* __restrict__ P, const float* __restrict__ k1,
    const float* __restrict__ v1, float* __restrict__ y)
{
    __shared__ h2 kl2[NSRP * 8];
    __shared__ h2 vp2[NPAIR * 16];
    __shared__ float pl[128][17];
    const int bh = blockIdx.x;
    const int b = bh / 3, h = bh % 3;
    const float4* ks = (const float4*)(k1 + (size_t)bh * NSR * 16);
    const float4* vs = (const float4*)(v1 + (size_t)bh * NSR * 16);
    const float4 z4 = make_float4(0.f, 0.f, 0.f, 0.f);

    for (int idx = threadIdx.x; idx < NSRP * 4; idx += 256) {
        int m = idx >> 2;
        stage_k(kl2, (m < NSR) ? ks[idx] : z4, idx);
    }
    for (int idx = threadIdx.x; idx < NPAIR * 2; idx += 256) {
        int pr = idx >> 1, hf = idx & 1;
        int ma = 2 * pr, mb = ma + 1;
        float4 a0 = vs[ma * 4 + hf * 2], a1 = vs[ma * 4 + hf * 2 + 1];
        float4 b0 = z4, b1 = z4;
        if (mb < NSR) { b0 = vs[mb * 4 + hf * 2]; b1 = vs[mb * 4 + hf * 2 + 1]; }
        h8* vph = (h8*)vp2;
        vph[pr * 4 + hf * 2]     = packV(a0, b0);
        vph[pr * 4 + hf * 2 + 1] = packV(a1, b1);
    }
    __syncthreads();

    const int khalf = threadIdx.x >> 7;
    const int qloc = threadIdx.x & 127;
    const int n0 = blockIdx.y * 128 + qloc;
    const bool ok = (n0 < NTOK);
    const int nq = ok ? n0 : (NTOK - 1);

    float qa[16]; h2 qh[8];
    ld16_g(P + ((size_t)b * NTOK + nq) * 288 + 96 + h * 16, qa);
    cvt_qs(qa, qh);

    float a[16];
#pragma unroll
    for (int e = 0; e < 16; e++) a[e] = 0.f;
    float l = 0.f;

    attn_runp(kl2, vp2, khalf ? 86 : 0, khalf ? NPAIR : 86, qh, a, l);
    if (khalf) l -= 1.f;    // pad key 343: p=exp(0)=1, V=0

    if (khalf) {
#pragma unroll
        for (int e = 0; e < 16; e++) pl[qloc][e] = a[e];
        pl[qloc][16] = l;
    }
    __syncthreads();
    if (!khalf && ok) {
#pragma unroll
        for (int e = 0; e < 16; e++) a[e] += pl[qloc][e];
        l += pl[qloc][16];
        st16_g(y + ((size_t)b * NTOK + n0) * 96 + h * 16, a, 1.f / l);
    }
}

// ---------------------------------------------------------------------------
// K4: branch-2 windowed attention -> y[:, :, 48:96]
// grid 768 = (b,h,win) x 2 q-halves, 384 threads: 172 q x 2 key-halves (paired).
// ---------------------------------------------------------------------------
__global__ __launch_bounds__(384) void k_attn2(
    const float* __restrict__ P, float* __restrict__ y)
{
    __shared__ h2 kl2[NSRP * 8];
    __shared__ h2 vp2[NPAIR * 16];
    __shared__ float pl[172][17];
    const int pb = blockIdx.x >> 1, qhalf = blockIdx.x & 1;
    const int b = pb / 192;
    const int rem = pb % 192;
    const int h = rem / 64, win = rem % 64;
    const int wh = win >> 4, ww = (win >> 2) & 3, wd = win & 3;
    const int h0 = wh * 7, w0 = ww * 7, d0 = wd * 7;
    const float4 z4 = make_float4(0.f, 0.f, 0.f, 0.f);

    for (int idx = threadIdx.x; idx < NSRP * 4; idx += 384) {
        int m = idx >> 2, e4 = idx & 3;
        float4 kv = z4;
        if (m < NSR) {
            int a = m / 49, bw = (m / 7) % 7, cw = m % 7;
            int n = (h0 + a) * WD + (w0 + bw) * 28 + (d0 + cw);
            kv = *(const float4*)(P + ((size_t)b * NTOK + n) * 288 + 192 + h * 16 + e4 * 4);
        }
        stage_k(kl2, kv, idx);
    }
    for (int idx = threadIdx.x; idx < NPAIR * 2; idx += 384) {
        int pr = idx >> 1, hf = idx & 1;
        int ma = 2 * pr, mb = ma + 1;
        int aa = ma / 49, ab = (ma / 7) % 7, ac = ma % 7;
        int na = (h0 + aa) * WD + (w0 + ab) * 28 + (d0 + ac);
        const float* sa = P + ((size_t)b * NTOK + na) * 288 + 240 + h * 16 + hf * 8;
        float4 a0 = *(const float4*)sa, a1 = *(const float4*)(sa + 4);
        float4 b0 = z4, b1 = z4;
        if (mb < NSR) {
            int ba = mb / 49, bbw = (mb / 7) % 7, bc = mb % 7;
            int nb = (h0 + ba) * WD + (w0 + bbw) * 28 + (d0 + bc);
            const float* sb = P + ((size_t)b * NTOK + nb) * 288 + 240 + h * 16 + hf * 8;
            b0 = *(const float4*)sb; b1 = *(const float4*)(sb + 4);
        }
        h8* vph = (h8*)vp2;
        vph[pr * 4 + hf * 2]     = packV(a0, b0);
        vph[pr * 4 + hf * 2 + 1] = packV(a1, b1);
    }
    __syncthreads();

    const int khalf = (threadIdx.x >= 192) ? 1 : 0;
    const int qloc = khalf ? (threadIdx.x - 192) : threadIdx.x;
    const int q = qhalf * 172 + qloc;
    const bool ok = (qloc < 172) && (q < NSR);
    const int qc = ok ? q : 0;

    int ai = qc / 49, bi = (qc / 7) % 7, ci = qc % 7;
    int n0 = (h0 + ai) * WD + (w0 + bi) * 28 + (d0 + ci);

    float qa[16]; h2 qh[8];
    ld16_g(P + ((size_t)b * NTOK + n0) * 288 + 144 + h * 16, qa);
    cvt_qs(qa, qh);

    float a[16];
#pragma unroll
    for (int e = 0; e < 16; e++) a[e] = 0.f;
    float l = 0.f;

    attn_runp(kl2, vp2, khalf ? 86 : 0, khalf ? NPAIR : 86, qh, a, l);
    if (khalf) l -= 1.f;    // pad key 343

    if (khalf && ok) {
#pragma unroll
        for (int e = 0; e < 16; e++) pl[qloc][e] = a[e];
        pl[qloc][16] = l;
    }
    __syncthreads();
    if (!khalf && ok) {
#pragma unroll
        for (int e = 0; e < 16; e++) a[e] += pl[qloc][e];
        l += pl[qloc][16];
        st16_g(y + ((size_t)b * NTOK + n0) * 96 + 48 + h * 16, a, 1.f / l);
    }
}

// ---------------------------------------------------------------------------
// K5: LePE depthwise 3x3x3 conv over t = P[:,0:96]; y += lepe
// ---------------------------------------------------------------------------
__global__ __launch_bounds__(256) void k_lepe(
    const float* __restrict__ P, const float* __restrict__ cwT,
    const float* __restrict__ cb, float* __restrict__ y)
{
    const int p = blockIdx.x;
    const int l = (p & 7) * 515 + (p >> 3);
    if (l >= LNB) return;
    const int id = l * 256 + threadIdx.x;
    const int g4 = (id % 24) * 4;
    const int nl = id / 24;
    const int n = nl % NTOK;
    const int h = n / WD, w = (n / 28) % 28, d = n % 28;
    const float* Pb = P + (size_t)(nl - n) * 288;

    float4 acc = *(const float4*)(cb + g4);
#pragma unroll
    for (int tap = 0; tap < 27; tap++) {
        const int dh = tap / 9 - 1, dw = (tap / 3) % 3 - 1, dd = tap % 3 - 1;
        const int hh = h + dh, ww = w + dw, d2 = d + dd;
        const bool v = ((unsigned)hh < 28u) & ((unsigned)ww < 28u) & ((unsigned)d2 < 28u);
        const int nn = v ? (hh * WD + ww * 28 + d2) : n;
        const float m = v ? 1.f : 0.f;
        float4 pv = *(const float4*)(Pb + (size_t)nn * 288 + g4);
        float4 wv = *(const float4*)(cwT + tap * 96 + g4);
        acc.x += pv.x * (wv.x * m);
        acc.y += pv.y * (wv.y * m);
        acc.z += pv.z * (wv.z * m);
        acc.w += pv.w * (wv.w * m);
    }
    float4* yp = (float4*)(y + (size_t)nl * 96 + g4);
    float4 cur = *yp;
    cur.x += acc.x; cur.y += acc.y; cur.z += acc.z; cur.w += acc.w;
    *yp = cur;
}

// ---------------------------------------------------------------------------
// K6: out = y @ proj_w^T + proj_b  — register-tiled GEMM, 64 tok x 48 j tile
// ---------------------------------------------------------------------------
__global__ __launch_bounds__(192) void k_out(
    const float* __restrict__ y, const float* __restrict__ proj_w,
    const float* __restrict__ proj_b, float* __restrict__ out)
{
    __shared__ float xT[96][68];
    __shared__ float wT[96][52];

    const int base = blockIdx.x * 64;
    const int j0 = blockIdx.y * 48;

    for (int it = threadIdx.x; it < 1536; it += 192) {
        int t = it & 63, cq = it >> 6;           // lanes share cq, walk t
        float4 v = *(const float4*)(y + (size_t)(base + t) * 96 + cq * 4);
        xT[cq * 4 + 0][t] = v.x; xT[cq * 4 + 1][t] = v.y;
        xT[cq * 4 + 2][t] = v.z; xT[cq * 4 + 3][t] = v.w;
    }
    for (int it = threadIdx.x; it < 1152; it += 192) {
        int jl = it % 48, cq = it / 48;
        float4 v = *(const float4*)(proj_w + (size_t)(j0 + jl) * 96 + cq * 4);
        wT[cq * 4 + 0][jl] = v.x; wT[cq * 4 + 1][jl] = v.y;
        wT[cq * 4 + 2][jl] = v.z; wT[cq * 4 + 3][jl] = v.w;
    }
    __syncthreads();

    const int tq = threadIdx.x & 15;
    const int jq = threadIdx.x >> 4;
    float acc[4][4];
#pragma unroll
    for (int i = 0; i < 4; i++)
#pragma unroll
        for (int jj = 0; jj < 4; jj++) acc[i][jj] = 0.f;

    for (int c = 0; c < 96; c++) {
        float4 xv = *(const float4*)(&xT[c][tq * 4]);
        float4 wv = *(const float4*)(&wT[c][jq * 4]);
        float xa[4] = {xv.x, xv.y, xv.z, xv.w};
        float wa[4] = {wv.x, wv.y, wv.z, wv.w};
#pragma unroll
        for (int i = 0; i < 4; i++)
#pragma unroll
            for (int jj = 0; jj < 4; jj++) acc[i][jj] += xa[i] * wa[jj];
    }

    float4 bias = *(const float4*)(proj_b + j0 + jq * 4);
#pragma unroll
    for (int i = 0; i < 4; i++) {
        int t = base + tq * 4 + i;
        float4 o = make_float4(acc[i][0] + bias.x, acc[i][1] + bias.y,
                               acc[i][2] + bias.z, acc[i][3] + bias.w);
        *(float4*)(out + (size_t)t * 96 + j0 + jq * 4) = o;
    }
}

extern "C" void kernel_launch(void* const* d_in, const int* in_sizes, int n_in,
                              void* d_out, int out_size, void* d_ws, size_t ws_size,
                              hipStream_t stream) {
    const float* x          = (const float*)d_in[0];
    const float* lepe_lin_w = (const float*)d_in[4];
    const float* lepe_lin_b = (const float*)d_in[5];
    const float* lepe_conv_w= (const float*)d_in[6];
    const float* lepe_conv_b= (const float*)d_in[7];
    const float* sr_w       = (const float*)d_in[8];
    const float* sr_b       = (const float*)d_in[9];
    const float* norm_g     = (const float*)d_in[10];
    const float* norm_b     = (const float*)d_in[11];
    const float* q1_w       = (const float*)d_in[12];
    const float* kv1_w      = (const float*)d_in[13];
    const float* q2_w       = (const float*)d_in[14];
    const float* kv2_w      = (const float*)d_in[15];
    const float* proj_w     = (const float*)d_in[16];
    const float* proj_b     = (const float*)d_in[17];

    float* P   = (float*)d_ws;                        // [B*N][288]
    float* k1  = P + (size_t)BB * NTOK * 288;         // [B][3][343][16]
    float* v1  = k1 + (size_t)BB * 3 * NSR * 16;
    float* y   = v1 + (size_t)BB * 3 * NSR * 16;      // [B*N][96]
    float* pa  = y + (size_t)BB * NTOK * 96;          // [686][16][96]
    float* Wt  = pa + (size_t)NSITE * 16 * 96;        // [1536][96] float4
    float* cwT = Wt + (size_t)1536 * 96 * 4;          // [27][96]

    k_wt<<<587, 256, 0, stream>>>(sr_w, (float4*)Wt, lepe_conv_w, cwT);
    k_proj<<<dim3(686, 6), 192, 0, stream>>>(x, lepe_lin_w, lepe_lin_b, q1_w, q2_w, kv2_w, P);
    k_sr_a<<<dim3(86, 16), 128, 0, stream>>>(x, (const float4*)Wt, pa);
    k_sr_b<<<NSITE, 96, 0, stream>>>(pa, sr_b, norm_g, norm_b, kv1_w, k1, v1);
    k_attn1<<<dim3(6, 172), 256, 0, stream>>>(P, k1, v1, y);
    k_attn2<<<768, 384, 0, stream>>>(P, y);
    k_lepe<<<4120, 256, 0, stream>>>(P, cwT, lepe_conv_b, y);
    k_out<<<dim3(686, 2), 192, 0, stream>>>(y, proj_w, proj_b, (float*)d_out);
}

// Round 13
// 354.497 us; speedup vs baseline: 1.4216x; 1.0228x over previous
//
#include <hip/hip_runtime.h>

#define BB 2
#define NTOK 21952      // 28^3
#define CC 96
#define WD 784          // 28*28
#define NSR 343         // 7^3
#define NSRP 344        // padded (key 343 = zeros)
#define NPAIR 172
#define NSITE 686       // BB*NSR
#define SCALE 0.25f
#define LN_EPS 1e-5f
#define LNB 4116        // k_lepe logical blocks

typedef _Float16 half_t;
typedef __attribute__((ext_vector_type(2))) _Float16 h2;
typedef __attribute__((ext_vector_type(8))) _Float16 h8;
typedef __attribute__((ext_vector_type(2))) __fp16 fp16x2;
union HU { h8 v; h2 p[4]; };

__device__ __forceinline__ h2 pk2(float a, float b) {
    return __builtin_bit_cast(h2, __builtin_amdgcn_cvt_pkrtz(a, b));
}

// ---------------------------------------------------------------------------
// K0: transpose sr_w [96][6144] -> Wt4[1536][96]; also lepe_conv_w -> cwT[27][96]
// ---------------------------------------------------------------------------
__global__ __launch_bounds__(256) void k_wt(
    const float* __restrict__ w, float4* __restrict__ Wt4,
    const float* __restrict__ cw, float* __restrict__ cwT)
{
    const int id = blockIdx.x * 256 + threadIdx.x;
    if (id < 96 * 1536) {
        const int co = id % 96, kbg = id / 96;
        const float4 v = *(const float4*)(w + (size_t)co * 6144 + 4 * kbg);
        Wt4[(size_t)kbg * 96 + co] = v;
    } else if (id < 96 * 1536 + 27 * 96) {
        const int id2 = id - 96 * 1536;
        const int tap = id2 / 96, c = id2 % 96;
        cwT[tap * 96 + c] = cw[c * 27 + tap];
    }
}

// ---------------------------------------------------------------------------
// K1: P[token][288] = x @ [lepe_lin | q1 | q2 | kv2]^T  (+ lepe bias on 0:96)
// packed-f16 fdot2 GEMM: 64 tok x 48 j tile, thread = 4x4, K=48 c-pairs.
// ---------------------------------------------------------------------------
__global__ __launch_bounds__(192) void k_proj(
    const float* __restrict__ x, const float* __restrict__ lepe_w,
    const float* __restrict__ lepe_b, const float* __restrict__ q1_w,
    const float* __restrict__ q2_w, const float* __restrict__ kv2_w,
    float* __restrict__ P)
{
    __shared__ h2 xh[48][68];   // [c-pair][token], row 272B (16B aligned)
    __shared__ h2 wh[48][52];   // [c-pair][j],    row 208B (16B aligned)

    const int base = blockIdx.x * 64;
    const int j0 = blockIdx.y * 48;

    for (int it = threadIdx.x; it < 1536; it += 192) {
        int t = it & 63, cq = it >> 6;           // lanes share cq, walk t
        float4 v = *(const float4*)(x + (size_t)(base + t) * 96 + cq * 4);
        xh[cq * 2 + 0][t] = pk2(v.x, v.y);
        xh[cq * 2 + 1][t] = pk2(v.z, v.w);
    }
    for (int it = threadIdx.x; it < 1152; it += 192) {
        int jl = it % 48, cq = it / 48;          // lanes walk jl
        int jg = j0 + jl;
        const float* wrow;
        if (jg < 96)       wrow = lepe_w + jg * 96;
        else if (jg < 144) wrow = q1_w + (jg - 96) * 96;
        else if (jg < 192) wrow = q2_w + (jg - 144) * 96;
        else               wrow = kv2_w + (jg - 192) * 96;
        float4 v = *(const float4*)(wrow + cq * 4);
        wh[cq * 2 + 0][jl] = pk2(v.x, v.y);
        wh[cq * 2 + 1][jl] = pk2(v.z, v.w);
    }
    __syncthreads();

    const int tq = threadIdx.x & 15;
    const int jq = threadIdx.x >> 4;
    float acc[4][4];
#pragma unroll
    for (int i = 0; i < 4; i++)
#pragma unroll
        for (int jj = 0; jj < 4; jj++) acc[i][jj] = 0.f;

    for (int cp = 0; cp < 48; cp++) {
        HU xv, wv;
        xv.v = *(const h8*)(&xh[cp][tq * 4]);
        wv.v = *(const h8*)(&wh[cp][jq * 4]);
#pragma unroll
        for (int i = 0; i < 4; i++)
#pragma unroll
            for (int jj = 0; jj < 4; jj++)
                acc[i][jj] = __builtin_amdgcn_fdot2(xv.p[i], wv.p[jj], acc[i][jj], false);
    }

    float bias[4];
#pragma unroll
    for (int jj = 0; jj < 4; jj++) {
        int jg = j0 + jq * 4 + jj;
        bias[jj] = (jg < 96) ? lepe_b[jg] : 0.f;
    }
#pragma unroll
    for (int i = 0; i < 4; i++) {
        int t = base + tq * 4 + i;
        float4 o = make_float4(acc[i][0] + bias[0], acc[i][1] + bias[1],
                               acc[i][2] + bias[2], acc[i][3] + bias[3]);
        *(float4*)(P + (size_t)t * 288 + j0 + jq * 4) = o;
    }
}

// ---------------------------------------------------------------------------
// K2a: SR conv split-K GEMM. grid (86 site-groups x 16 k-splits), block 128.
// ---------------------------------------------------------------------------
__global__ __launch_bounds__(128) void k_sr_a(
    const float* __restrict__ x, const float4* __restrict__ Wt4,
    float* __restrict__ pa)
{
    __shared__ float patch[8 * 384];
    const int sg = blockIdx.x, ks = blockIdx.y;
    const int ci0 = ks * 6;

    for (int pr = threadIdx.x; pr < 512; pr += 128) {
        int s = pr >> 6, p = pr & 63;
        int s_g = sg * 8 + s; if (s_g > NSITE - 1) s_g = NSITE - 1;
        int b = s_g / NSR, sloc = s_g % NSR;
        int si = sloc / 49, sj = (sloc / 7) % 7, sk = sloc % 7;
        int a = p >> 4, q = (p >> 2) & 3, r = p & 3;
        int n = (4 * si + a) * WD + (4 * sj + q) * 28 + (4 * sk + r);
        const float2* xp = (const float2*)(x + ((size_t)b * NTOK + n) * 96 + ci0);
        float2 v0 = xp[0], v1 = xp[1], v2 = xp[2];
        int base = s * 384 + p;
        patch[base +   0] = v0.x; patch[base +  64] = v0.y;
        patch[base + 128] = v1.x; patch[base + 192] = v1.y;
        patch[base + 256] = v2.x; patch[base + 320] = v2.y;
    }
    __syncthreads();

    const int co = threadIdx.x;
    if (co >= 96) return;
    float acc[8];
#pragma unroll
    for (int s = 0; s < 8; s++) acc[s] = 0.f;
    const float4* p4 = (const float4*)patch;
    const float4* wb = Wt4 + (size_t)ks * 96 * 96 + co;
    for (int kb = 0; kb < 96; kb++) {
        float4 w = wb[(size_t)kb * 96];
#pragma unroll
        for (int s = 0; s < 8; s++) {
            float4 pv = p4[s * 96 + kb];
            acc[s] += pv.x * w.x + pv.y * w.y + pv.z * w.z + pv.w * w.w;
        }
    }
#pragma unroll
    for (int s = 0; s < 8; s++) {
        int s_g = sg * 8 + s;
        if (s_g < NSITE)
            pa[((size_t)s_g * 16 + ks) * 96 + co] = acc[s];
    }
}

// ---------------------------------------------------------------------------
// K2b: reduce 16 partials + bias + LN + GELU + kv1 -> k1/v1 [B][3][343][16]
// ---------------------------------------------------------------------------
__global__ __launch_bounds__(96) void k_sr_b(
    const float* __restrict__ pa, const float* __restrict__ sr_b,
    const float* __restrict__ norm_g, const float* __restrict__ norm_b,
    const float* __restrict__ kv1_w, float* __restrict__ k1,
    float* __restrict__ v1)
{
    __shared__ float xs_s[96];
    __shared__ float gx[96];
    const int s_g = blockIdx.x;
    const int b = s_g / NSR, s = s_g % NSR;
    const int co = threadIdx.x;

    const float* pp = pa + (size_t)s_g * 16 * 96 + co;
    float acc = sr_b[co];
#pragma unroll
    for (int ks = 0; ks < 16; ks++) acc += pp[ks * 96];
    xs_s[co] = acc;
    __syncthreads();

    float m = 0.f, m2 = 0.f;
    for (int c = 0; c < 96; c++) { float v = xs_s[c]; m += v; m2 += v * v; }
    m *= (1.f / 96.f);
    float var = m2 * (1.f / 96.f) - m * m;
    float t = (acc - m) * rsqrtf(var + LN_EPS) * norm_g[co] + norm_b[co];
    gx[co] = 0.5f * t * (1.f + erff(t * 0.70710678118654752f));
    __syncthreads();

    const float4* w4 = (const float4*)(kv1_w + co * 96);
    const float4* g4 = (const float4*)gx;
    float a2 = 0.f;
#pragma unroll
    for (int c = 0; c < 24; c++) {
        float4 w = w4[c]; float4 g = g4[c];
        a2 += g.x * w.x + g.y * w.y + g.z * w.z + g.w * w.w;
    }
    int pair = co / 48, h = (co % 48) / 16, e = co % 16;
    float* dst = pair ? v1 : k1;
    dst[(((size_t)b * 3 + h) * NSR + s) * 16 + e] = a2;
}

// ---------------------------------------------------------------------------
// helpers
// ---------------------------------------------------------------------------
__device__ __forceinline__ void ld16_g(const float* p, float* o) {
    const float4* p4 = (const float4*)p;
#pragma unroll
    for (int i = 0; i < 4; i++) {
        float4 v = p4[i];
        o[4 * i] = v.x; o[4 * i + 1] = v.y; o[4 * i + 2] = v.z; o[4 * i + 3] = v.w;
    }
}
__device__ __forceinline__ void st16_g(float* p, const float* o, float scl) {
    float4* p4 = (float4*)p;
#pragma unroll
    for (int i = 0; i < 4; i++)
        p4[i] = make_float4(o[4 * i] * scl, o[4 * i + 1] * scl,
                            o[4 * i + 2] * scl, o[4 * i + 3] * scl);
}
// q -> f16 with SCALE folded in
__device__ __forceinline__ void cvt_qs(const float* qa, h2* qh) {
#pragma unroll
    for (int i = 0; i < 8; i++)
        qh[i] = pk2(qa[2 * i] * SCALE, qa[2 * i + 1] * SCALE);
}
// K row (2 float4 = 8 elems) -> 4 h2 at kl2[4*idx..]
__device__ __forceinline__ void stage_k(h2* kl2, const float4 kv, int idx) {
    kl2[2 * idx]     = pk2(kv.x, kv.y);
    kl2[2 * idx + 1] = pk2(kv.z, kv.w);
}
// pack pair-interleaved V
__device__ __forceinline__ h8 packV(const float4 A, const float4 B) {
    HU u;
    u.p[0] = pk2(A.x, B.x);
    u.p[1] = pk2(A.y, B.y);
    u.p[2] = pk2(A.z, B.z);
    u.p[3] = pk2(A.w, B.w);
    return u.v;
}

// ---------------------------------------------------------------------------
// paired attention core: pairs [pr0,pr1), q pre-scaled f16, V pair-interleaved.
// ---------------------------------------------------------------------------
__device__ __forceinline__ void attn_runp(
    const h2* kl2, const h2* vp2, int pr0, int pr1, const h2* qh,
    float* a, float& l)
{
    const h8* kp = (const h8*)kl2;
    const h8* vp = (const h8*)vp2;
    for (int pr = pr0; pr < pr1; pr++) {
        HU ka0, kb0, ka1, kb1, v0, v1, v2m, v3;
        ka0.v = kp[4 * pr];     kb0.v = kp[4 * pr + 1];
        ka1.v = kp[4 * pr + 2]; kb1.v = kp[4 * pr + 3];
        v0.v = vp[4 * pr];      v1.v = vp[4 * pr + 1];
        v2m.v = vp[4 * pr + 2]; v3.v = vp[4 * pr + 3];
        float s0 = 0.f, s1 = 0.f;
#pragma unroll
        for (int i = 0; i < 4; i++) {
            s0 = __builtin_amdgcn_fdot2(qh[i], ka0.p[i], s0, false);
            s0 = __builtin_amdgcn_fdot2(qh[4 + i], kb0.p[i], s0, false);
            s1 = __builtin_amdgcn_fdot2(qh[i], ka1.p[i], s1, false);
            s1 = __builtin_amdgcn_fdot2(qh[4 + i], kb1.p[i], s1, false);
        }
        float p0 = __expf(s0), p1 = __expf(s1);
        l += p0 + p1;
        h2 pp = pk2(p0, p1);
#pragma unroll
        for (int i = 0; i < 4; i++) {
            a[i]      = __builtin_amdgcn_fdot2(pp, v0.p[i],  a[i],      false);
            a[4 + i]  = __builtin_amdgcn_fdot2(pp, v1.p[i],  a[4 + i],  false);
            a[8 + i]  = __builtin_amdgcn_fdot2(pp, v2m.p[i], a[8 + i],  false);
            a[12 + i] = __builtin_amdgcn_fdot2(pp, v3.p[i],  a[12 + i], false);
        }
    }
}

// ---------------------------------------------------------------------------
// K3: branch-1 SR attention -> y[:, :, 0:48]
// ---------------------------------------------------------------------------
__global__ __launch_bounds__(256) void k_attn1(
    const float* __restrict__ P, const float* __restrict__ k1,
    const float* __restrict__ v1, float* __restrict__ y)
{
    __shared__ h2 kl2[NSRP * 8];
    __shared__ h2 vp2[NPAIR * 16];
    __shared__ float pl[128][17];
    const int bh = blockIdx.x;
    const int b = bh / 3, h = bh % 3;
    const float4* ks = (const float4*)(k1 + (size_t)bh * NSR * 16);
    const float4* vs = (const float4*)(v1 + (size_t)bh * NSR * 16);
    const float4 z4 = make_float4(0.f, 0.f, 0.f, 0.f);

    for (int idx = threadIdx.x; idx < NSRP * 4; idx += 256) {
        int m = idx >> 2;
        stage_k(kl2, (m < NSR) ? ks[idx] : z4, idx);
    }
    for (int idx = threadIdx.x; idx < NPAIR * 2; idx += 256) {
        int pr = idx >> 1, hf = idx & 1;
        int ma = 2 * pr, mb = ma + 1;
        float4 a0 = vs[ma * 4 + hf * 2], a1 = vs[ma * 4 + hf * 2 + 1];
        float4 b0 = z4, b1 = z4;
        if (mb < NSR) { b0 = vs[mb * 4 + hf * 2]; b1 = vs[mb * 4 + hf * 2 + 1]; }
        h8* vph = (h8*)vp2;
        vph[pr * 4 + hf * 2]     = packV(a0, b0);
        vph[pr * 4 + hf * 2 + 1] = packV(a1, b1);
    }
    __syncthreads();

    const int khalf = threadIdx.x >> 7;
    const int qloc = threadIdx.x & 127;
    const int n0 = blockIdx.y * 128 + qloc;
    const bool ok = (n0 < NTOK);
    const int nq = ok ? n0 : (NTOK - 1);

    float qa[16]; h2 qh[8];
    ld16_g(P + ((size_t)b * NTOK + nq) * 288 + 96 + h * 16, qa);
    cvt_qs(qa, qh);

    float a[16];
#pragma unroll
    for (int e = 0; e < 16; e++) a[e] = 0.f;
    float l = 0.f;

    attn_runp(kl2, vp2, khalf ? 86 : 0, khalf ? NPAIR : 86, qh, a, l);
    if (khalf) l -= 1.f;    // pad key 343: p=exp(0)=1, V=0

    if (khalf) {
#pragma unroll
        for (int e = 0; e < 16; e++) pl[qloc][e] = a[e];
        pl[qloc][16] = l;
    }
    __syncthreads();
    if (!khalf && ok) {
#pragma unroll
        for (int e = 0; e < 16; e++) a[e] += pl[qloc][e];
        l += pl[qloc][16];
        st16_g(y + ((size_t)b * NTOK + n0) * 96 + h * 16, a, 1.f / l);
    }
}

// ---------------------------------------------------------------------------
// K4: branch-2 windowed attention -> y[:, :, 48:96]
// ---------------------------------------------------------------------------
__global__ __launch_bounds__(384) void k_attn2(
    const float* __restrict__ P, float* __restrict__ y)
{
    __shared__ h2 kl2[NSRP * 8];
    __shared__ h2 vp2[NPAIR * 16];
    __shared__ float pl[172][17];
    const int pb = blockIdx.x >> 1, qhalf = blockIdx.x & 1;
    const int b = pb / 192;
    const int rem = pb % 192;
    const int h = rem / 64, win = rem % 64;
    const int wh = win >> 4, ww = (win >> 2) & 3, wd = win & 3;
    const int h0 = wh * 7, w0 = ww * 7, d0 = wd * 7;
    const float4 z4 = make_float4(0.f, 0.f, 0.f, 0.f);

    for (int idx = threadIdx.x; idx < NSRP * 4; idx += 384) {
        int m = idx >> 2, e4 = idx & 3;
        float4 kv = z4;
        if (m < NSR) {
            int a = m / 49, bw = (m / 7) % 7, cw = m % 7;
            int n = (h0 + a) * WD + (w0 + bw) * 28 + (d0 + cw);
            kv = *(const float4*)(P + ((size_t)b * NTOK + n) * 288 + 192 + h * 16 + e4 * 4);
        }
        stage_k(kl2, kv, idx);
    }
    for (int idx = threadIdx.x; idx < NPAIR * 2; idx += 384) {
        int pr = idx >> 1, hf = idx & 1;
        int ma = 2 * pr, mb = ma + 1;
        int aa = ma / 49, ab = (ma / 7) % 7, ac = ma % 7;
        int na = (h0 + aa) * WD + (w0 + ab) * 28 + (d0 + ac);
        const float* sa = P + ((size_t)b * NTOK + na) * 288 + 240 + h * 16 + hf * 8;
        float4 a0 = *(const float4*)sa, a1 = *(const float4*)(sa + 4);
        float4 b0 = z4, b1 = z4;
        if (mb < NSR) {
            int ba = mb / 49, bbw = (mb / 7) % 7, bc = mb % 7;
            int nb = (h0 + ba) * WD + (w0 + bbw) * 28 + (d0 + bc);
            const float* sb = P + ((size_t)b * NTOK + nb) * 288 + 240 + h * 16 + hf * 8;
            b0 = *(const float4*)sb; b1 = *(const float4*)(sb + 4);
        }
        h8* vph = (h8*)vp2;
        vph[pr * 4 + hf * 2]     = packV(a0, b0);
        vph[pr * 4 + hf * 2 + 1] = packV(a1, b1);
    }
    __syncthreads();

    const int khalf = (threadIdx.x >= 192) ? 1 : 0;
    const int qloc = khalf ? (threadIdx.x - 192) : threadIdx.x;
    const int q = qhalf * 172 + qloc;
    const bool ok = (qloc < 172) && (q < NSR);
    const int qc = ok ? q : 0;

    int ai = qc / 49, bi = (qc / 7) % 7, ci = qc % 7;
    int n0 = (h0 + ai) * WD + (w0 + bi) * 28 + (d0 + ci);

    float qa[16]; h2 qh[8];
    ld16_g(P + ((size_t)b * NTOK + n0) * 288 + 144 + h * 16, qa);
    cvt_qs(qa, qh);

    float a[16];
#pragma unroll
    for (int e = 0; e < 16; e++) a[e] = 0.f;
    float l = 0.f;

    attn_runp(kl2, vp2, khalf ? 86 : 0, khalf ? NPAIR : 86, qh, a, l);
    if (khalf) l -= 1.f;    // pad key 343

    if (khalf && ok) {
#pragma unroll
        for (int e = 0; e < 16; e++) pl[qloc][e] = a[e];
        pl[qloc][16] = l;
    }
    __syncthreads();
    if (!khalf && ok) {
#pragma unroll
        for (int e = 0; e < 16; e++) a[e] += pl[qloc][e];
        l += pl[qloc][16];
        st16_g(y + ((size_t)b * NTOK + n0) * 96 + 48 + h * 16, a, 1.f / l);
    }
}

// ---------------------------------------------------------------------------
// K5: LePE depthwise 3x3x3 conv over t = P[:,0:96]; y += lepe
// ---------------------------------------------------------------------------
__global__ __launch_bounds__(256) void k_lepe(
    const float* __restrict__ P, const float* __restrict__ cwT,
    const float* __restrict__ cb, float* __restrict__ y)
{
    const int p = blockIdx.x;
    const int l = (p & 7) * 515 + (p >> 3);
    if (l >= LNB) return;
    const int id = l * 256 + threadIdx.x;
    const int g4 = (id % 24) * 4;
    const int nl = id / 24;
    const int n = nl % NTOK;
    const int h = n / WD, w = (n / 28) % 28, d = n % 28;
    const float* Pb = P + (size_t)(nl - n) * 288;

    float4 acc = *(const float4*)(cb + g4);
#pragma unroll
    for (int tap = 0; tap < 27; tap++) {
        const int dh = tap / 9 - 1, dw = (tap / 3) % 3 - 1, dd = tap % 3 - 1;
        const int hh = h + dh, ww = w + dw, d2 = d + dd;
        const bool v = ((unsigned)hh < 28u) & ((unsigned)ww < 28u) & ((unsigned)d2 < 28u);
        const int nn = v ? (hh * WD + ww * 28 + d2) : n;
        const float m = v ? 1.f : 0.f;
        float4 pv = *(const float4*)(Pb + (size_t)nn * 288 + g4);
        float4 wv = *(const float4*)(cwT + tap * 96 + g4);
        acc.x += pv.x * (wv.x * m);
        acc.y += pv.y * (wv.y * m);
        acc.z += pv.z * (wv.z * m);
        acc.w += pv.w * (wv.w * m);
    }
    float4* yp = (float4*)(y + (size_t)nl * 96 + g4);
    float4 cur = *yp;
    cur.x += acc.x; cur.y += acc.y; cur.z += acc.z; cur.w += acc.w;
    *yp = cur;
}

// ---------------------------------------------------------------------------
// K6: out = y @ proj_w^T + proj_b  — packed-f16 fdot2 GEMM, 64 tok x 48 j tile
// ---------------------------------------------------------------------------
__global__ __launch_bounds__(192) void k_out(
    const float* __restrict__ y, const float* __restrict__ proj_w,
    const float* __restrict__ proj_b, float* __restrict__ out)
{
    __shared__ h2 xh[48][68];
    __shared__ h2 wh[48][52];

    const int base = blockIdx.x * 64;
    const int j0 = blockIdx.y * 48;

    for (int it = threadIdx.x; it < 1536; it += 192) {
        int t = it & 63, cq = it >> 6;
        float4 v = *(const float4*)(y + (size_t)(base + t) * 96 + cq * 4);
        xh[cq * 2 + 0][t] = pk2(v.x, v.y);
        xh[cq * 2 + 1][t] = pk2(v.z, v.w);
    }
    for (int it = threadIdx.x; it < 1152; it += 192) {
        int jl = it % 48, cq = it / 48;
        float4 v = *(const float4*)(proj_w + (size_t)(j0 + jl) * 96 + cq * 4);
        wh[cq * 2 + 0][jl] = pk2(v.x, v.y);
        wh[cq * 2 + 1][jl] = pk2(v.z, v.w);
    }
    __syncthreads();

    const int tq = threadIdx.x & 15;
    const int jq = threadIdx.x >> 4;
    float acc[4][4];
#pragma unroll
    for (int i = 0; i < 4; i++)
#pragma unroll
        for (int jj = 0; jj < 4; jj++) acc[i][jj] = 0.f;

    for (int cp = 0; cp < 48; cp++) {
        HU xv, wv;
        xv.v = *(const h8*)(&xh[cp][tq * 4]);
        wv.v = *(const h8*)(&wh[cp][jq * 4]);
#pragma unroll
        for (int i = 0; i < 4; i++)
#pragma unroll
            for (int jj = 0; jj < 4; jj++)
                acc[i][jj] = __builtin_amdgcn_fdot2(xv.p[i], wv.p[jj], acc[i][jj], false);
    }

    float4 bias = *(const float4*)(proj_b + j0 + jq * 4);
#pragma unroll
    for (int i = 0; i < 4; i++) {
        int t = base + tq * 4 + i;
        float4 o = make_float4(acc[i][0] + bias.x, acc[i][1] + bias.y,
                               acc[i][2] + bias.z, acc[i][3] + bias.w);
        *(float4*)(out + (size_t)t * 96 + j0 + jq * 4) = o;
    }
}

extern "C" void kernel_launch(void* const* d_in, const int* in_sizes, int n_in,
                              void* d_out, int out_size, void* d_ws, size_t ws_size,
                              hipStream_t stream) {
    const float* x          = (const float*)d_in[0];
    const float* lepe_lin_w = (const float*)d_in[4];
    const float* lepe_lin_b = (const float*)d_in[5];
    const float* lepe_conv_w= (const float*)d_in[6];
    const float* lepe_conv_b= (const float*)d_in[7];
    const float* sr_w       = (const float*)d_in[8];
    const float* sr_b       = (const float*)d_in[9];
    const float* norm_g     = (const float*)d_in[10];
    const float* norm_b     = (const float*)d_in[11];
    const float* q1_w       = (const float*)d_in[12];
    const float* kv1_w      = (const float*)d_in[13];
    const float* q2_w       = (const float*)d_in[14];
    const float* kv2_w      = (const float*)d_in[15];
    const float* proj_w     = (const float*)d_in[16];
    const float* proj_b     = (const float*)d_in[17];

    float* P   = (float*)d_ws;                        // [B*N][288]
    float* k1  = P + (size_t)BB * NTOK * 288;         // [B][3][343][16]
    float* v1  = k1 + (size_t)BB * 3 * NSR * 16;
    float* y   = v1 + (size_t)BB * 3 * NSR * 16;      // [B*N][96]
    float* pa  = y + (size_t)BB * NTOK * 96;          // [686][16][96]
    float* Wt  = pa + (size_t)NSITE * 16 * 96;        // [1536][96] float4
    float* cwT = Wt + (size_t)1536 * 96 * 4;          // [27][96]

    k_wt<<<587, 256, 0, stream>>>(sr_w, (float4*)Wt, lepe_conv_w, cwT);
    k_proj<<<dim3(686, 6), 192, 0, stream>>>(x, lepe_lin_w, lepe_lin_b, q1_w, q2_w, kv2_w, P);
    k_sr_a<<<dim3(86, 16), 128, 0, stream>>>(x, (const float4*)Wt, pa);
    k_sr_b<<<NSITE, 96, 0, stream>>>(pa, sr_b, norm_g, norm_b, kv1_w, k1, v1);
    k_attn1<<<dim3(6, 172), 256, 0, stream>>>(P, k1, v1, y);
    k_attn2<<<768, 384, 0, stream>>>(P, y);
    k_lepe<<<4120, 256, 0, stream>>>(P, cwT, lepe_conv_b, y);
    k_out<<<dim3(686, 2), 192, 0, stream>>>(y, proj_w, proj_b, (float*)d_out);
}